// Round 10
// baseline (351.577 us; speedup 1.0000x reference)
//
#include <hip/hip_runtime.h>
#include <cstdint>
#include <cstddef>

#define NN 20000   // nodes
#define NE 320000  // edges
#define D  128     // embed dim
#define TW 8       // towers
#define FT 16      // per-tower features
#define NL 3       // layers
#define NS 4096    // subgraphs
#define INR 512    // (L+1)*D

typedef unsigned short u16;
typedef __attribute__((ext_vector_type(8))) short short8;
typedef __attribute__((ext_vector_type(4))) float f32x4;

__device__ __forceinline__ float b2f(short s) {
    return __uint_as_float(((unsigned)(u16)s) << 16);
}
__device__ __forceinline__ u16 f2b(float f) {
    unsigned u = __float_as_uint(f);
    return (u16)((u + 0x7FFF + ((u >> 16) & 1)) >> 16);   // RNE
}

// ---------------- scan (block 0: deg->eoff over NN, block 1: scnt->soff over NS) ----

__global__ void scan2_kernel(const int* __restrict__ cnt0, int* __restrict__ off0,
                             const int* __restrict__ cnt1, int* __restrict__ off1) {
    __shared__ int lds[1024];
    const int tid = threadIdx.x;
    const int* cnt = blockIdx.x ? cnt1 : cnt0;
    int*       off = blockIdx.x ? off1 : off0;
    const int n   = blockIdx.x ? NS : NN;
    const int per = (n + 1023) >> 10;
    const int s = tid * per;
    const int e = min(s + per, n);
    int sum = 0;
    for (int i = s; i < e; ++i) sum += cnt[i];
    lds[tid] = sum;
    __syncthreads();
    for (int o = 1; o < 1024; o <<= 1) {
        int v = (tid >= o) ? lds[tid - o] : 0;
        __syncthreads();
        if (tid >= o) lds[tid] += v;
        __syncthreads();
    }
    int base = (tid == 0) ? 0 : lds[tid - 1];
    for (int i = s; i < e; ++i) { off[i] = base; base += cnt[i]; }
    if (tid == 1023) off[n] = lds[1023];
}

__global__ void fill_kernel(const int* __restrict__ ei, const int* __restrict__ sub,
                            const int* __restrict__ eoff, int* __restrict__ ecur,
                            int* __restrict__ csr,
                            const int* __restrict__ soff, int* __restrict__ scur,
                            int* __restrict__ snodes) {
    int i = blockIdx.x * blockDim.x + threadIdx.x;
    if (i < NE) {
        int dd = ei[NE + i];
        int p = atomicAdd(&ecur[dd], 1);
        csr[eoff[dd] + p] = ei[i];          // src
    }
    if (i < NN) {
        int g = sub[i];
        int p = atomicAdd(&scur[g], 1);
        snodes[soff[g] + p] = i;
    }
}

// ---------------- merged prep ----------------
// blocks: 0..23 tower-fold | 24..279 weff | 280..311 beff | 312..335 packB
//         | 336..1585 x->bf16 + x-pool atomics | 1586..2835 count (deg/scnt atomics)
__global__ __launch_bounds__(256)
void prep_kernel(const float* __restrict__ pre_w, const float* __restrict__ pre_b,
                 const float* __restrict__ post_w,
                 float* __restrict__ cw, float* __restrict__ cv,
                 const float* __restrict__ op_w, const float* __restrict__ op_b,
                 const float* __restrict__ gma, const float* __restrict__ bta,
                 const float* __restrict__ mean, const float* __restrict__ var,
                 float* __restrict__ wefft, float* __restrict__ beff,
                 const float* __restrict__ lin_w, u16* __restrict__ packB,
                 const float* __restrict__ x, u16* __restrict__ xbf,
                 const int* __restrict__ ei, const int* __restrict__ sub,
                 int* __restrict__ deg, int* __restrict__ scnt,
                 float* __restrict__ pooled) {
    const int b = blockIdx.x;
    const int tid = threadIdx.x;
    if (b < 24) {                          // ---- tower fold (fp32)
        const int lt = b;
        const int dd = tid >> 4;
        const int ff = tid & 15;
        const float* PW = pre_w  + (size_t)lt * (FT * 2 * FT);
        const float* QW = post_w + (size_t)lt * (FT * 2 * FT);
        const float* PB = pre_b  + (size_t)lt * FT;
        float m1 = QW[dd * 32 + ff];
        float m2 = 0.f, m3 = 0.f, v = 0.f;
        for (int k = 0; k < FT; ++k) {
            float pb = QW[dd * 32 + 16 + k];
            m2 = fmaf(pb, PW[k * 32 + ff], m2);
            m3 = fmaf(pb, PW[k * 32 + 16 + ff], m3);
            if (ff == 0) v = fmaf(pb, PB[k], v);
        }
        float* o = cw + ((size_t)lt * 16 + dd) * 48;
        o[ff] = m1; o[16 + ff] = m2; o[32 + ff] = m3;
        if (ff == 0) cv[lt * 16 + dd] = v;
    } else if (b < 280) {                  // ---- wefft[j][d] = op_w[d][j]*scale[j]
        int i = (b - 24) * 256 + tid;
        int j = i >> 7, d = i & (D - 1);
        float sc = gma[j] * rsqrtf(var[j] + 1e-5f);
        wefft[(size_t)j * D + d] = op_w[(size_t)d * INR + j] * sc;
    } else if (b < 312) {                  // ---- beff rows (4/block)
        const int d = (b - 280) * 4 + (tid >> 6);
        const int lane = tid & 63;
        float acc = 0.f;
        for (int j = lane; j < INR; j += 64) {
            float sc = gma[j] * rsqrtf(var[j] + 1e-5f);
            float sh = bta[j] - mean[j] * sc;
            acc = fmaf(op_w[(size_t)d * INR + j], sh, acc);
        }
#pragma unroll
        for (int o = 32; o; o >>= 1) acc += __shfl_down(acc, o);
        if (lane == 0) beff[d] = acc + op_b[d];
    } else if (b < 336) {                  // ---- pack lin_w into per-lane MFMA B-frags
        const int lt = b - 312;            // l*8 + ct
        const int l  = lt >> 3, ct = lt & 7;
        const int ks = tid >> 6;           // 0..3
        const int lane = tid & 63;
        const int col = ct * 16 + (lane & 15);
        const int k0  = ks * 32 + ((lane >> 4) & 3) * 8;
        const float* lw = lin_w + (size_t)l * D * D + (size_t)col * D + k0;
        u16* o = packB + ((size_t)(lt * 4 + ks) * 64 + lane) * 8;
#pragma unroll
        for (int j = 0; j < 8; ++j) o[j] = f2b(lw[j]);
    } else if (b < 1586) {                 // ---- x -> bf16 copy + x pooling (2048 elems/block)
        const size_t base = (size_t)(b - 336) * 2048 + (size_t)tid * 8;
        const int node = (int)(base >> 7);
        const int d0   = (int)(base & 127);
        float4 a = *(const float4*)(x + base);
        float4 c = *(const float4*)(x + base + 4);
        u16 o[8] = { f2b(a.x), f2b(a.y), f2b(a.z), f2b(a.w),
                     f2b(c.x), f2b(c.y), f2b(c.z), f2b(c.w) };
        uint4 u;
        u.x = (unsigned)o[0] | ((unsigned)o[1] << 16);
        u.y = (unsigned)o[2] | ((unsigned)o[3] << 16);
        u.z = (unsigned)o[4] | ((unsigned)o[5] << 16);
        u.w = (unsigned)o[6] | ((unsigned)o[7] << 16);
        *(uint4*)(xbf + base) = u;
        float* pb = pooled + (size_t)sub[node] * INR + d0;   // x occupies cols 0..127
        atomicAdd(pb + 0, a.x); atomicAdd(pb + 1, a.y);
        atomicAdd(pb + 2, a.z); atomicAdd(pb + 3, a.w);
        atomicAdd(pb + 4, c.x); atomicAdd(pb + 5, c.y);
        atomicAdd(pb + 6, c.z); atomicAdd(pb + 7, c.w);
    } else {                               // ---- count (deg / scnt atomics)
        int i = (b - 1586) * 256 + tid;
        if (i < NE) atomicAdd(&deg[ei[NE + i]], 1);
        if (i < NN) atomicAdd(&scnt[sub[i]], 1);
    }
}

// ---------------- fused gather + PNA update (+ pooled accumulation) ----------------
// 1 block = 16 nodes, 512 threads (8 waves).
// Phase G: wave w gathers nodes 2w,2w+1 (neighbor-sum -> SG fp32; x-row -> XL bf16).
// Phase T: fp32 tower from LDS. Phase M: bf16 MFMA matvec; epilogue writes h(l+1)
// and atomically accumulates into pooled[sub][.] (fp32).
__global__ __launch_bounds__(512, 4)
void fgu_kernel(const u16* __restrict__ hin, const int* __restrict__ eoff,
                const int* __restrict__ csr, const int* __restrict__ deg,
                const int* __restrict__ sub,
                const float* __restrict__ cw, const float* __restrict__ cv,
                const float* __restrict__ post_b, const u16* __restrict__ packB,
                const float* __restrict__ lin_b, u16* __restrict__ hout,
                float* __restrict__ pooled, int l) {
    __shared__ float SG[16 * 128];     // gathered neighbor sums (8 KB)
    __shared__ u16   XL[16 * 128];     // staged x rows (4 KB)
    __shared__ u16   OBS[16 * 136];    // tower output, padded stride (4.25 KB)
    __shared__ float DG[16];
    __shared__ int   SUBL[16];

    const int tid  = threadIdx.x;
    const int lane = tid & 63;
    const int wv   = tid >> 6;         // 0..7
    const int n0   = blockIdx.x << 4;

    // MFMA B-fragments for this wave's column tile
    short8 BF[4];
    {
        const short8* pB = (const short8*)packB + (size_t)((l * 8 + wv) * 4) * 64 + lane;
#pragma unroll
        for (int ks = 0; ks < 4; ++ks) BF[ks] = pB[ks * 64];
    }
    const float bl = lin_b[l * D + wv * 16 + (lane & 15)];
    if (tid < 16) SUBL[tid] = sub[n0 + tid];

    // ---- Phase G: gather 2 nodes per wave
    {
        const int half = lane >> 5;
        const int q    = lane & 31;
#pragma unroll
        for (int u = 0; u < 2; ++u) {
            const int ln = wv * 2 + u;
            const int node = n0 + ln;
            ((unsigned*)XL)[ln * 64 + lane] =
                ((const unsigned*)(hin + (size_t)node * D))[lane];
            if (lane == 0) DG[ln] = (float)deg[node];
            const int e0 = eoff[node], e1 = eoff[node + 1];
            const uint2* h2 = (const uint2*)hin;
            float ax = 0.f, ay = 0.f, az = 0.f, aw = 0.f;
            int e = e0;
            for (; e + 8 <= e1; e += 8) {
#pragma unroll
                for (int k = 0; k < 4; ++k) {
                    int s = csr[e + 2 * k + half];
                    uint2 v = h2[(size_t)s * 32 + q];
                    ax += __uint_as_float(v.x << 16);
                    ay += __uint_as_float(v.x & 0xFFFF0000u);
                    az += __uint_as_float(v.y << 16);
                    aw += __uint_as_float(v.y & 0xFFFF0000u);
                }
            }
            for (; e < e1; e += 2) {
                int idx = e + half;
                bool valid = idx < e1;
                int s = valid ? csr[idx] : 0;
                uint2 v = h2[(size_t)s * 32 + q];
                if (valid) {
                    ax += __uint_as_float(v.x << 16);
                    ay += __uint_as_float(v.x & 0xFFFF0000u);
                    az += __uint_as_float(v.y << 16);
                    aw += __uint_as_float(v.y & 0xFFFF0000u);
                }
            }
            ax += __shfl_xor(ax, 32);
            ay += __shfl_xor(ay, 32);
            az += __shfl_xor(az, 32);
            aw += __shfl_xor(aw, 32);
            if (half == 0) {
                float4 r; r.x = ax; r.y = ay; r.z = az; r.w = aw;
                ((float4*)SG)[ln * 32 + q] = r;
            }
        }
    }
    __syncthreads();

    // ---- Phase T: fp32 tower, 4 nodes per thread (si group), all operands in LDS
    {
        const int si  = tid >> 7;      // 0..3
        const int d   = tid & 127;
        const int t16 = d & ~15;
        const int dd  = d & 15;
        const float* wb = cw + ((size_t)(l * TW + (d >> 4)) * 16 + dd) * 48;
        const float4* wb4 = (const float4*)wb;
        float m1[16], m2[16], m3[16];
#pragma unroll
        for (int qq = 0; qq < 4; ++qq) {
            float4 t1 = wb4[qq], t2 = wb4[4 + qq], t3 = wb4[8 + qq];
            m1[qq*4+0]=t1.x; m1[qq*4+1]=t1.y; m1[qq*4+2]=t1.z; m1[qq*4+3]=t1.w;
            m2[qq*4+0]=t2.x; m2[qq*4+1]=t2.y; m2[qq*4+2]=t2.z; m2[qq*4+3]=t2.w;
            m3[qq*4+0]=t3.x; m3[qq*4+1]=t3.y; m3[qq*4+2]=t3.z; m3[qq*4+3]=t3.w;
        }
        const float vq = cv[(l * TW + (d >> 4)) * 16 + dd];
        const float cb = post_b[l * D + d];
#pragma unroll
        for (int u = 0; u < 4; ++u) {
            const int ln = si * 4 + u;
            const short8* hp = (const short8*)&XL[ln * 128 + t16];
            short8 hx0 = hp[0], hx1 = hp[1];
            const float4* sp = (const float4*)&SG[ln * 128 + t16];
            float4 sv0 = sp[0], sv1 = sp[1], sv2 = sp[2], sv3 = sp[3];
            float ax = 0.f, am = 0.f, as2 = 0.f;
#pragma unroll
            for (int j = 0; j < 8; ++j) {
                float xf = b2f(hx0[j]);
                ax = fmaf(m1[j], xf, ax);
                am = fmaf(m2[j], xf, am);
            }
#pragma unroll
            for (int j = 0; j < 8; ++j) {
                float xf = b2f(hx1[j]);
                ax = fmaf(m1[8 + j], xf, ax);
                am = fmaf(m2[8 + j], xf, am);
            }
            as2 = fmaf(m3[0], sv0.x, as2); as2 = fmaf(m3[1], sv0.y, as2);
            as2 = fmaf(m3[2], sv0.z, as2); as2 = fmaf(m3[3], sv0.w, as2);
            as2 = fmaf(m3[4], sv1.x, as2); as2 = fmaf(m3[5], sv1.y, as2);
            as2 = fmaf(m3[6], sv1.z, as2); as2 = fmaf(m3[7], sv1.w, as2);
            as2 = fmaf(m3[8], sv2.x, as2); as2 = fmaf(m3[9], sv2.y, as2);
            as2 = fmaf(m3[10], sv2.z, as2); as2 = fmaf(m3[11], sv2.w, as2);
            as2 = fmaf(m3[12], sv3.x, as2); as2 = fmaf(m3[13], sv3.y, as2);
            as2 = fmaf(m3[14], sv3.z, as2); as2 = fmaf(m3[15], sv3.w, as2);
            OBS[ln * 136 + d] = f2b(cb + ax + as2 + DG[ln] * (am + vq));
        }
    }
    __syncthreads();

    // ---- Phase M: MFMA matvec, wave wv computes OUT[0:16][wv*16 : +16]
    f32x4 c = {0.f, 0.f, 0.f, 0.f};
#pragma unroll
    for (int ks = 0; ks < 4; ++ks) {
        const short8 a = *(const short8*)((const char*)OBS +
                            (lane & 15) * 272 + (ks * 4 + (lane >> 4)) * 16);
        c = __builtin_amdgcn_mfma_f32_16x16x32_bf16(a, BF[ks], c, 0, 0, 0);
    }
    const int d_epi = wv * 16 + (lane & 15);
    const bool write_h = (l < NL - 1);
    float* pcol = pooled + (size_t)(l + 1) * 128 + d_epi;
#pragma unroll
    for (int r = 0; r < 4; ++r) {
        const int ln = (lane >> 4) * 4 + r;          // C: col=lane&15, row=(lane>>4)*4+r
        const int node = n0 + ln;
        float v = fmaxf(c[r] + bl, 0.f);
        if (write_h) hout[(size_t)node * D + d_epi] = f2b(v);
        atomicAdd(pcol + (size_t)SUBL[ln] * INR, v);
    }
}

// ---------------- fused BN + out GEMM (reads pooled) ----------------
// 16 subgraphs/block, 512 threads = 4 j-quarters x 128 d
__global__ __launch_bounds__(512)
void out_kernel(const float* __restrict__ pooled, const float* __restrict__ wefft,
                const float* __restrict__ beff, float* __restrict__ out) {
    __shared__ float sm[16 * INR];   // 32 KB; phase2 reuses as partial[4][16][128]
    const int tid = threadIdx.x;
    const int q = tid >> 7;
    const int d = tid & 127;
    const int s0 = blockIdx.x * 16;
    {
        const float4* src = (const float4*)(pooled + (size_t)s0 * INR);
        float4* dst = (float4*)sm;
        for (int i = tid; i < 16 * INR / 4; i += 512) dst[i] = src[i];
    }
    __syncthreads();
    float acc[16];
#pragma unroll
    for (int i = 0; i < 16; ++i) acc[i] = 0.f;
    for (int jj4 = 0; jj4 < 32; ++jj4) {
        const int j0 = q * 128 + jj4 * 4;
        float wv0 = wefft[(size_t)(j0 + 0) * D + d];
        float wv1 = wefft[(size_t)(j0 + 1) * D + d];
        float wv2 = wefft[(size_t)(j0 + 2) * D + d];
        float wv3 = wefft[(size_t)(j0 + 3) * D + d];
#pragma unroll
        for (int i = 0; i < 16; ++i) {
            float4 pv = *(const float4*)&sm[i * INR + j0];
            acc[i] = fmaf(pv.x, wv0, acc[i]);
            acc[i] = fmaf(pv.y, wv1, acc[i]);
            acc[i] = fmaf(pv.z, wv2, acc[i]);
            acc[i] = fmaf(pv.w, wv3, acc[i]);
        }
    }
    __syncthreads();
#pragma unroll
    for (int i = 0; i < 16; ++i) sm[(q * 16 + i) * 128 + d] = acc[i];
    __syncthreads();
    const float bb = beff[d];
#pragma unroll
    for (int ii = 0; ii < 4; ++ii) {
        int i = q * 4 + ii;
        float v = sm[i * 128 + d] + sm[(16 + i) * 128 + d]
                + sm[(32 + i) * 128 + d] + sm[(48 + i) * 128 + d];
        out[(size_t)(s0 + i) * D + d] = v + bb;
    }
}

// ---------------- launch ----------------

extern "C" void kernel_launch(void* const* d_in, const int* in_sizes, int n_in,
                              void* d_out, int out_size, void* d_ws, size_t ws_size,
                              hipStream_t stream) {
    const float* x      = (const float*)d_in[0];
    const int*   ei     = (const int*)d_in[1];
    const int*   sub    = (const int*)d_in[2];
    const float* pre_w  = (const float*)d_in[3];
    const float* pre_b  = (const float*)d_in[4];
    const float* post_w = (const float*)d_in[5];
    const float* post_b = (const float*)d_in[6];
    const float* lin_w  = (const float*)d_in[7];
    const float* lin_b  = (const float*)d_in[8];
    const float* bn_g   = (const float*)d_in[9];
    const float* bn_b   = (const float*)d_in[10];
    const float* bn_m   = (const float*)d_in[11];
    const float* bn_v   = (const float*)d_in[12];
    const float* op_w   = (const float*)d_in[13];
    const float* op_b   = (const float*)d_in[14];
    float* out = (float*)d_out;

    char* p = (char*)d_ws;
    auto alloc = [&](size_t bytes) -> char* {
        char* q = p;
        p += (bytes + 255) & ~(size_t)255;
        return q;
    };

    // zeroed group (contiguous): counters + pooled
    char* zero_start = p;
    int* deg  = (int*)alloc(sizeof(int) * NN);
    int* ecur = (int*)alloc(sizeof(int) * NN);
    int* scnt = (int*)alloc(sizeof(int) * NS);
    int* scur = (int*)alloc(sizeof(int) * NS);
    float* pooled = (float*)alloc(sizeof(float) * (size_t)NS * INR);
    size_t zero_span = (size_t)(p - zero_start);

    int* eoff   = (int*)alloc(sizeof(int) * (NN + 1));
    int* soff   = (int*)alloc(sizeof(int) * (NS + 1));
    int* csr    = (int*)alloc(sizeof(int) * NE);
    int* snodes = (int*)alloc(sizeof(int) * NN);
    u16* xbf    = (u16*)alloc(sizeof(u16) * (size_t)NN * D);
    u16* h1     = (u16*)alloc(sizeof(u16) * (size_t)NN * D);
    u16* h2     = (u16*)alloc(sizeof(u16) * (size_t)NN * D);
    float* wefft  = (float*)alloc(sizeof(float) * (size_t)INR * D);
    float* beff   = (float*)alloc(sizeof(float) * D);
    float* cw     = (float*)alloc(sizeof(float) * NL * TW * 16 * 48);
    float* cv     = (float*)alloc(sizeof(float) * NL * TW * 16);
    u16* packB    = (u16*)alloc(sizeof(u16) * NL * 8 * 4 * 64 * 8);

    hipMemsetAsync(zero_start, 0, zero_span, stream);

    prep_kernel<<<2836, 256, 0, stream>>>(pre_w, pre_b, post_w, cw, cv,
                                          op_w, op_b, bn_g, bn_b, bn_m, bn_v,
                                          wefft, beff, lin_w, packB, x, xbf,
                                          ei, sub, deg, scnt, pooled);
    scan2_kernel<<<2, 1024, 0, stream>>>(deg, eoff, scnt, soff);
    fill_kernel<<<(NE + 255) / 256, 256, 0, stream>>>(ei, sub, eoff, ecur, csr,
                                                      soff, scur, snodes);

    const u16* hs[4] = { xbf, h1, h2, h1 /*dummy, not written*/ };
    for (int l = 0; l < NL; ++l) {
        fgu_kernel<<<NN / 16, 512, 0, stream>>>(hs[l], eoff, csr, deg, sub,
                                                cw, cv, post_b, packB, lin_b,
                                                (u16*)hs[l + 1], pooled, l);
    }

    out_kernel<<<NS / 16, 512, 0, stream>>>(pooled, wefft, beff, out);
}

// Round 11
// 273.696 us; speedup vs baseline: 1.2846x; 1.2846x over previous
//
#include <hip/hip_runtime.h>
#include <cstdint>
#include <cstddef>

#define NN 20000   // nodes
#define NE 320000  // edges
#define D  128     // embed dim
#define TW 8       // towers
#define FT 16      // per-tower features
#define NL 3       // layers
#define NS 4096    // subgraphs
#define INR 512    // (L+1)*D

typedef unsigned short u16;
typedef __attribute__((ext_vector_type(8))) short short8;
typedef __attribute__((ext_vector_type(4))) float f32x4;

__device__ __forceinline__ float b2f(short s) {
    return __uint_as_float(((unsigned)(u16)s) << 16);
}
__device__ __forceinline__ u16 f2b(float f) {
    unsigned u = __float_as_uint(f);
    return (u16)((u + 0x7FFF + ((u >> 16) & 1)) >> 16);   // RNE
}

// ---------------- scan (block 0: deg->eoff over NN, block 1: scnt->soff over NS) ----

__global__ void scan2_kernel(const int* __restrict__ cnt0, int* __restrict__ off0,
                             const int* __restrict__ cnt1, int* __restrict__ off1) {
    __shared__ int lds[1024];
    const int tid = threadIdx.x;
    const int* cnt = blockIdx.x ? cnt1 : cnt0;
    int*       off = blockIdx.x ? off1 : off0;
    const int n   = blockIdx.x ? NS : NN;
    const int per = (n + 1023) >> 10;
    const int s = tid * per;
    const int e = min(s + per, n);
    int sum = 0;
    for (int i = s; i < e; ++i) sum += cnt[i];
    lds[tid] = sum;
    __syncthreads();
    for (int o = 1; o < 1024; o <<= 1) {
        int v = (tid >= o) ? lds[tid - o] : 0;
        __syncthreads();
        if (tid >= o) lds[tid] += v;
        __syncthreads();
    }
    int base = (tid == 0) ? 0 : lds[tid - 1];
    for (int i = s; i < e; ++i) { off[i] = base; base += cnt[i]; }
    if (tid == 1023) off[n] = lds[1023];
}

__global__ void fill_kernel(const int* __restrict__ ei, const int* __restrict__ sub,
                            const int* __restrict__ eoff, int* __restrict__ ecur,
                            int* __restrict__ csr,
                            const int* __restrict__ soff, int* __restrict__ scur,
                            int* __restrict__ snodes) {
    int i = blockIdx.x * blockDim.x + threadIdx.x;
    if (i < NE) {
        int dd = ei[NE + i];
        int p = atomicAdd(&ecur[dd], 1);
        csr[eoff[dd] + p] = ei[i];          // src
    }
    if (i < NN) {
        int g = sub[i];
        int p = atomicAdd(&scur[g], 1);
        snodes[soff[g] + p] = i;
    }
}

// ---------------- merged prep ----------------
// blocks: 0..23 tower-fold | 24..279 weff | 280..311 beff | 312..335 packB
//         | 336..1585 x->bf16 | 1586..2835 count (deg/scnt atomics)
__global__ __launch_bounds__(256)
void prep_kernel(const float* __restrict__ pre_w, const float* __restrict__ pre_b,
                 const float* __restrict__ post_w,
                 float* __restrict__ cw, float* __restrict__ cv,
                 const float* __restrict__ op_w, const float* __restrict__ op_b,
                 const float* __restrict__ gma, const float* __restrict__ bta,
                 const float* __restrict__ mean, const float* __restrict__ var,
                 float* __restrict__ wefft, float* __restrict__ beff,
                 const float* __restrict__ lin_w, u16* __restrict__ packB,
                 const float* __restrict__ x, u16* __restrict__ xbf,
                 const int* __restrict__ ei, const int* __restrict__ sub,
                 int* __restrict__ deg, int* __restrict__ scnt) {
    const int b = blockIdx.x;
    const int tid = threadIdx.x;
    if (b < 24) {                          // ---- tower fold (fp32)
        const int lt = b;
        const int dd = tid >> 4;
        const int ff = tid & 15;
        const float* PW = pre_w  + (size_t)lt * (FT * 2 * FT);
        const float* QW = post_w + (size_t)lt * (FT * 2 * FT);
        const float* PB = pre_b  + (size_t)lt * FT;
        float m1 = QW[dd * 32 + ff];
        float m2 = 0.f, m3 = 0.f, v = 0.f;
        for (int k = 0; k < FT; ++k) {
            float pb = QW[dd * 32 + 16 + k];
            m2 = fmaf(pb, PW[k * 32 + ff], m2);
            m3 = fmaf(pb, PW[k * 32 + 16 + ff], m3);
            if (ff == 0) v = fmaf(pb, PB[k], v);
        }
        float* o = cw + ((size_t)lt * 16 + dd) * 48;
        o[ff] = m1; o[16 + ff] = m2; o[32 + ff] = m3;
        if (ff == 0) cv[lt * 16 + dd] = v;
    } else if (b < 280) {                  // ---- wefft[j][d] = op_w[d][j]*scale[j]
        int i = (b - 24) * 256 + tid;
        int j = i >> 7, d = i & (D - 1);
        float sc = gma[j] * rsqrtf(var[j] + 1e-5f);
        wefft[(size_t)j * D + d] = op_w[(size_t)d * INR + j] * sc;
    } else if (b < 312) {                  // ---- beff rows (4/block)
        const int d = (b - 280) * 4 + (tid >> 6);
        const int lane = tid & 63;
        float acc = 0.f;
        for (int j = lane; j < INR; j += 64) {
            float sc = gma[j] * rsqrtf(var[j] + 1e-5f);
            float sh = bta[j] - mean[j] * sc;
            acc = fmaf(op_w[(size_t)d * INR + j], sh, acc);
        }
#pragma unroll
        for (int o = 32; o; o >>= 1) acc += __shfl_down(acc, o);
        if (lane == 0) beff[d] = acc + op_b[d];
    } else if (b < 336) {                  // ---- pack lin_w into per-lane MFMA B-frags
        const int lt = b - 312;            // l*8 + ct
        const int l  = lt >> 3, ct = lt & 7;
        const int ks = tid >> 6;           // 0..3
        const int lane = tid & 63;
        const int col = ct * 16 + (lane & 15);
        const int k0  = ks * 32 + ((lane >> 4) & 3) * 8;
        const float* lw = lin_w + (size_t)l * D * D + (size_t)col * D + k0;
        u16* o = packB + ((size_t)(lt * 4 + ks) * 64 + lane) * 8;
#pragma unroll
        for (int j = 0; j < 8; ++j) o[j] = f2b(lw[j]);
    } else if (b < 1586) {                 // ---- x -> bf16 copy (2048 elems/block)
        const size_t base = (size_t)(b - 336) * 2048 + (size_t)tid * 8;
        float4 a = *(const float4*)(x + base);
        float4 c = *(const float4*)(x + base + 4);
        u16 o[8] = { f2b(a.x), f2b(a.y), f2b(a.z), f2b(a.w),
                     f2b(c.x), f2b(c.y), f2b(c.z), f2b(c.w) };
        uint4 u;
        u.x = (unsigned)o[0] | ((unsigned)o[1] << 16);
        u.y = (unsigned)o[2] | ((unsigned)o[3] << 16);
        u.z = (unsigned)o[4] | ((unsigned)o[5] << 16);
        u.w = (unsigned)o[6] | ((unsigned)o[7] << 16);
        *(uint4*)(xbf + base) = u;
    } else {                               // ---- count (deg / scnt atomics)
        int i = (b - 1586) * 256 + tid;
        if (i < NE) atomicAdd(&deg[ei[NE + i]], 1);
        if (i < NN) atomicAdd(&scnt[sub[i]], 1);
    }
}

// ---------------- fused gather + PNA update ----------------
// 1 block = 16 nodes, 512 threads (8 waves).
// Phase G: wave w gathers nodes 2w,2w+1 (16-edge unroll: 8 row-loads in flight/half).
// Phase T: fp32 tower from LDS. Phase M: bf16 MFMA matvec vs prepacked lin fragments.
__global__ __launch_bounds__(512, 4)
void fgu_kernel(const u16* __restrict__ hin, const int* __restrict__ eoff,
                const int* __restrict__ csr, const int* __restrict__ deg,
                const float* __restrict__ cw, const float* __restrict__ cv,
                const float* __restrict__ post_b, const u16* __restrict__ packB,
                const float* __restrict__ lin_b, u16* __restrict__ hout, int l) {
    __shared__ float SG[16 * 128];     // gathered neighbor sums (8 KB)
    __shared__ u16   XL[16 * 128];     // staged x rows (4 KB)
    __shared__ u16   OBS[16 * 136];    // tower output, padded stride (4.25 KB)
    __shared__ float DG[16];

    const int tid  = threadIdx.x;
    const int lane = tid & 63;
    const int wv   = tid >> 6;         // 0..7
    const int n0   = blockIdx.x << 4;

    // MFMA B-fragments for this wave's column tile
    short8 BF[4];
    {
        const short8* pB = (const short8*)packB + (size_t)((l * 8 + wv) * 4) * 64 + lane;
#pragma unroll
        for (int ks = 0; ks < 4; ++ks) BF[ks] = pB[ks * 64];
    }
    const float bl = lin_b[l * D + wv * 16 + (lane & 15)];

    // ---- Phase G: gather 2 nodes per wave
    {
        const int half = lane >> 5;
        const int q    = lane & 31;
        const uint2* h2 = (const uint2*)hin;
#pragma unroll
        for (int u = 0; u < 2; ++u) {
            const int ln = wv * 2 + u;
            const int node = n0 + ln;
            ((unsigned*)XL)[ln * 64 + lane] =
                ((const unsigned*)(hin + (size_t)node * D))[lane];
            if (lane == 0) DG[ln] = (float)deg[node];
            const int e0 = eoff[node], e1 = eoff[node + 1];
            float ax = 0.f, ay = 0.f, az = 0.f, aw = 0.f;
            int e = e0;
            // main: 16 edges/iter -> 8 independent row loads per half-wave
            for (; e + 16 <= e1; e += 16) {
                int s0 = csr[e +  0 + half], s1 = csr[e +  2 + half];
                int s2 = csr[e +  4 + half], s3 = csr[e +  6 + half];
                int s4 = csr[e +  8 + half], s5 = csr[e + 10 + half];
                int s6 = csr[e + 12 + half], s7 = csr[e + 14 + half];
                uint2 v0 = h2[(size_t)s0 * 32 + q];
                uint2 v1 = h2[(size_t)s1 * 32 + q];
                uint2 v2 = h2[(size_t)s2 * 32 + q];
                uint2 v3 = h2[(size_t)s3 * 32 + q];
                uint2 v4 = h2[(size_t)s4 * 32 + q];
                uint2 v5 = h2[(size_t)s5 * 32 + q];
                uint2 v6 = h2[(size_t)s6 * 32 + q];
                uint2 v7 = h2[(size_t)s7 * 32 + q];
                ax += __uint_as_float(v0.x << 16) + __uint_as_float(v1.x << 16)
                    + __uint_as_float(v2.x << 16) + __uint_as_float(v3.x << 16)
                    + __uint_as_float(v4.x << 16) + __uint_as_float(v5.x << 16)
                    + __uint_as_float(v6.x << 16) + __uint_as_float(v7.x << 16);
                ay += __uint_as_float(v0.x & 0xFFFF0000u) + __uint_as_float(v1.x & 0xFFFF0000u)
                    + __uint_as_float(v2.x & 0xFFFF0000u) + __uint_as_float(v3.x & 0xFFFF0000u)
                    + __uint_as_float(v4.x & 0xFFFF0000u) + __uint_as_float(v5.x & 0xFFFF0000u)
                    + __uint_as_float(v6.x & 0xFFFF0000u) + __uint_as_float(v7.x & 0xFFFF0000u);
                az += __uint_as_float(v0.y << 16) + __uint_as_float(v1.y << 16)
                    + __uint_as_float(v2.y << 16) + __uint_as_float(v3.y << 16)
                    + __uint_as_float(v4.y << 16) + __uint_as_float(v5.y << 16)
                    + __uint_as_float(v6.y << 16) + __uint_as_float(v7.y << 16);
                aw += __uint_as_float(v0.y & 0xFFFF0000u) + __uint_as_float(v1.y & 0xFFFF0000u)
                    + __uint_as_float(v2.y & 0xFFFF0000u) + __uint_as_float(v3.y & 0xFFFF0000u)
                    + __uint_as_float(v4.y & 0xFFFF0000u) + __uint_as_float(v5.y & 0xFFFF0000u)
                    + __uint_as_float(v6.y & 0xFFFF0000u) + __uint_as_float(v7.y & 0xFFFF0000u);
            }
            if (e + 8 <= e1) {
                int s0 = csr[e + 0 + half], s1 = csr[e + 2 + half];
                int s2 = csr[e + 4 + half], s3 = csr[e + 6 + half];
                uint2 v0 = h2[(size_t)s0 * 32 + q];
                uint2 v1 = h2[(size_t)s1 * 32 + q];
                uint2 v2 = h2[(size_t)s2 * 32 + q];
                uint2 v3 = h2[(size_t)s3 * 32 + q];
                ax += __uint_as_float(v0.x << 16) + __uint_as_float(v1.x << 16)
                    + __uint_as_float(v2.x << 16) + __uint_as_float(v3.x << 16);
                ay += __uint_as_float(v0.x & 0xFFFF0000u) + __uint_as_float(v1.x & 0xFFFF0000u)
                    + __uint_as_float(v2.x & 0xFFFF0000u) + __uint_as_float(v3.x & 0xFFFF0000u);
                az += __uint_as_float(v0.y << 16) + __uint_as_float(v1.y << 16)
                    + __uint_as_float(v2.y << 16) + __uint_as_float(v3.y << 16);
                aw += __uint_as_float(v0.y & 0xFFFF0000u) + __uint_as_float(v1.y & 0xFFFF0000u)
                    + __uint_as_float(v2.y & 0xFFFF0000u) + __uint_as_float(v3.y & 0xFFFF0000u);
                e += 8;
            }
            for (; e < e1; e += 2) {
                int idx = e + half;
                bool valid = idx < e1;
                int s = valid ? csr[idx] : 0;
                uint2 v = h2[(size_t)s * 32 + q];
                if (valid) {
                    ax += __uint_as_float(v.x << 16);
                    ay += __uint_as_float(v.x & 0xFFFF0000u);
                    az += __uint_as_float(v.y << 16);
                    aw += __uint_as_float(v.y & 0xFFFF0000u);
                }
            }
            ax += __shfl_xor(ax, 32);
            ay += __shfl_xor(ay, 32);
            az += __shfl_xor(az, 32);
            aw += __shfl_xor(aw, 32);
            if (half == 0) {
                float4 r; r.x = ax; r.y = ay; r.z = az; r.w = aw;
                ((float4*)SG)[ln * 32 + q] = r;
            }
        }
    }
    __syncthreads();

    // ---- Phase T: fp32 tower, 4 nodes per thread (si group), all operands in LDS
    {
        const int si  = tid >> 7;      // 0..3
        const int d   = tid & 127;
        const int t16 = d & ~15;
        const int dd  = d & 15;
        const float* wb = cw + ((size_t)(l * TW + (d >> 4)) * 16 + dd) * 48;
        const float4* wb4 = (const float4*)wb;
        float m1[16], m2[16], m3[16];
#pragma unroll
        for (int qq = 0; qq < 4; ++qq) {
            float4 t1 = wb4[qq], t2 = wb4[4 + qq], t3 = wb4[8 + qq];
            m1[qq*4+0]=t1.x; m1[qq*4+1]=t1.y; m1[qq*4+2]=t1.z; m1[qq*4+3]=t1.w;
            m2[qq*4+0]=t2.x; m2[qq*4+1]=t2.y; m2[qq*4+2]=t2.z; m2[qq*4+3]=t2.w;
            m3[qq*4+0]=t3.x; m3[qq*4+1]=t3.y; m3[qq*4+2]=t3.z; m3[qq*4+3]=t3.w;
        }
        const float vq = cv[(l * TW + (d >> 4)) * 16 + dd];
        const float cb = post_b[l * D + d];
#pragma unroll
        for (int u = 0; u < 4; ++u) {
            const int ln = si * 4 + u;
            const short8* hp = (const short8*)&XL[ln * 128 + t16];
            short8 hx0 = hp[0], hx1 = hp[1];
            const float4* sp = (const float4*)&SG[ln * 128 + t16];
            float4 sv0 = sp[0], sv1 = sp[1], sv2 = sp[2], sv3 = sp[3];
            float ax = 0.f, am = 0.f, as2 = 0.f;
#pragma unroll
            for (int j = 0; j < 8; ++j) {
                float xf = b2f(hx0[j]);
                ax = fmaf(m1[j], xf, ax);
                am = fmaf(m2[j], xf, am);
            }
#pragma unroll
            for (int j = 0; j < 8; ++j) {
                float xf = b2f(hx1[j]);
                ax = fmaf(m1[8 + j], xf, ax);
                am = fmaf(m2[8 + j], xf, am);
            }
            as2 = fmaf(m3[0], sv0.x, as2); as2 = fmaf(m3[1], sv0.y, as2);
            as2 = fmaf(m3[2], sv0.z, as2); as2 = fmaf(m3[3], sv0.w, as2);
            as2 = fmaf(m3[4], sv1.x, as2); as2 = fmaf(m3[5], sv1.y, as2);
            as2 = fmaf(m3[6], sv1.z, as2); as2 = fmaf(m3[7], sv1.w, as2);
            as2 = fmaf(m3[8], sv2.x, as2); as2 = fmaf(m3[9], sv2.y, as2);
            as2 = fmaf(m3[10], sv2.z, as2); as2 = fmaf(m3[11], sv2.w, as2);
            as2 = fmaf(m3[12], sv3.x, as2); as2 = fmaf(m3[13], sv3.y, as2);
            as2 = fmaf(m3[14], sv3.z, as2); as2 = fmaf(m3[15], sv3.w, as2);
            OBS[ln * 136 + d] = f2b(cb + ax + as2 + DG[ln] * (am + vq));
        }
    }
    __syncthreads();

    // ---- Phase M: MFMA matvec, wave wv computes OUT[0:16][wv*16 : +16]
    f32x4 c = {0.f, 0.f, 0.f, 0.f};
#pragma unroll
    for (int ks = 0; ks < 4; ++ks) {
        const short8 a = *(const short8*)((const char*)OBS +
                            (lane & 15) * 272 + (ks * 4 + (lane >> 4)) * 16);
        c = __builtin_amdgcn_mfma_f32_16x16x32_bf16(a, BF[ks], c, 0, 0, 0);
    }
    const int d_epi = wv * 16 + (lane & 15);
#pragma unroll
    for (int r = 0; r < 4; ++r) {
        const int node = n0 + (lane >> 4) * 4 + r;   // C: col=lane&15, row=(lane>>4)*4+r
        float v = fmaxf(c[r] + bl, 0.f);
        hout[(size_t)node * D + d_epi] = f2b(v);
    }
}

// ---------------- pooling (bf16 in, fp32 out), 2-node unroll ----------------

__global__ __launch_bounds__(128)
void pool_kernel(const u16* __restrict__ h0, const u16* __restrict__ h1,
                 const u16* __restrict__ h2, const u16* __restrict__ h3,
                 const int* __restrict__ soff, const int* __restrict__ snodes,
                 float* __restrict__ pooled) {
    const int s = blockIdx.x;
    const int t = threadIdx.x;
    const int seg = t >> 5, q = t & 31;
    const u16* hs = (seg == 0) ? h0 : (seg == 1) ? h1 : (seg == 2) ? h2 : h3;
    const uint2* hv = (const uint2*)hs;
    const int a0 = soff[s], a1 = soff[s + 1];
    float ax = 0.f, ay = 0.f, az = 0.f, aw = 0.f;
    int a = a0;
    for (; a + 2 <= a1; a += 2) {
        int na = snodes[a], nb = snodes[a + 1];
        uint2 va = hv[(size_t)na * 32 + q];
        uint2 vb = hv[(size_t)nb * 32 + q];
        ax += __uint_as_float(va.x << 16) + __uint_as_float(vb.x << 16);
        ay += __uint_as_float(va.x & 0xFFFF0000u) + __uint_as_float(vb.x & 0xFFFF0000u);
        az += __uint_as_float(va.y << 16) + __uint_as_float(vb.y << 16);
        aw += __uint_as_float(va.y & 0xFFFF0000u) + __uint_as_float(vb.y & 0xFFFF0000u);
    }
    if (a < a1) {
        int n = snodes[a];
        uint2 v = hv[(size_t)n * 32 + q];
        ax += __uint_as_float(v.x << 16);
        ay += __uint_as_float(v.x & 0xFFFF0000u);
        az += __uint_as_float(v.y << 16);
        aw += __uint_as_float(v.y & 0xFFFF0000u);
    }
    float4 r; r.x = ax; r.y = ay; r.z = az; r.w = aw;
    ((float4*)pooled)[(size_t)s * 128 + seg * 32 + q] = r;
}

// ---------------- fused BN + out GEMM ----------------

__global__ __launch_bounds__(512)
void out_kernel(const float* __restrict__ pooled, const float* __restrict__ wefft,
                const float* __restrict__ beff, float* __restrict__ out) {
    __shared__ float sm[16 * INR];   // 32 KB; phase2 reuses as partial[4][16][128]
    const int tid = threadIdx.x;
    const int q = tid >> 7;
    const int d = tid & 127;
    const int s0 = blockIdx.x * 16;
    {
        const float4* src = (const float4*)(pooled + (size_t)s0 * INR);
        float4* dst = (float4*)sm;
        for (int i = tid; i < 16 * INR / 4; i += 512) dst[i] = src[i];
    }
    __syncthreads();
    float acc[16];
#pragma unroll
    for (int i = 0; i < 16; ++i) acc[i] = 0.f;
    for (int jj4 = 0; jj4 < 32; ++jj4) {
        const int j0 = q * 128 + jj4 * 4;
        float wv0 = wefft[(size_t)(j0 + 0) * D + d];
        float wv1 = wefft[(size_t)(j0 + 1) * D + d];
        float wv2 = wefft[(size_t)(j0 + 2) * D + d];
        float wv3 = wefft[(size_t)(j0 + 3) * D + d];
#pragma unroll
        for (int i = 0; i < 16; ++i) {
            float4 pv = *(const float4*)&sm[i * INR + j0];
            acc[i] = fmaf(pv.x, wv0, acc[i]);
            acc[i] = fmaf(pv.y, wv1, acc[i]);
            acc[i] = fmaf(pv.z, wv2, acc[i]);
            acc[i] = fmaf(pv.w, wv3, acc[i]);
        }
    }
    __syncthreads();
#pragma unroll
    for (int i = 0; i < 16; ++i) sm[(q * 16 + i) * 128 + d] = acc[i];
    __syncthreads();
    const float bb = beff[d];
#pragma unroll
    for (int ii = 0; ii < 4; ++ii) {
        int i = q * 4 + ii;
        float v = sm[i * 128 + d] + sm[(16 + i) * 128 + d]
                + sm[(32 + i) * 128 + d] + sm[(48 + i) * 128 + d];
        out[(size_t)(s0 + i) * D + d] = v + bb;
    }
}

// ---------------- launch ----------------

extern "C" void kernel_launch(void* const* d_in, const int* in_sizes, int n_in,
                              void* d_out, int out_size, void* d_ws, size_t ws_size,
                              hipStream_t stream) {
    const float* x      = (const float*)d_in[0];
    const int*   ei     = (const int*)d_in[1];
    const int*   sub    = (const int*)d_in[2];
    const float* pre_w  = (const float*)d_in[3];
    const float* pre_b  = (const float*)d_in[4];
    const float* post_w = (const float*)d_in[5];
    const float* post_b = (const float*)d_in[6];
    const float* lin_w  = (const float*)d_in[7];
    const float* lin_b  = (const float*)d_in[8];
    const float* bn_g   = (const float*)d_in[9];
    const float* bn_b   = (const float*)d_in[10];
    const float* bn_m   = (const float*)d_in[11];
    const float* bn_v   = (const float*)d_in[12];
    const float* op_w   = (const float*)d_in[13];
    const float* op_b   = (const float*)d_in[14];
    float* out = (float*)d_out;

    char* p = (char*)d_ws;
    auto alloc = [&](size_t bytes) -> char* {
        char* q = p;
        p += (bytes + 255) & ~(size_t)255;
        return q;
    };

    char* zero_start = p;
    int* deg  = (int*)alloc(sizeof(int) * NN);
    int* ecur = (int*)alloc(sizeof(int) * NN);
    int* scnt = (int*)alloc(sizeof(int) * NS);
    int* scur = (int*)alloc(sizeof(int) * NS);
    size_t zero_span = (size_t)(p - zero_start);

    int* eoff   = (int*)alloc(sizeof(int) * (NN + 1));
    int* soff   = (int*)alloc(sizeof(int) * (NS + 1));
    int* csr    = (int*)alloc(sizeof(int) * NE);
    int* snodes = (int*)alloc(sizeof(int) * NN);
    u16* xbf    = (u16*)alloc(sizeof(u16) * (size_t)NN * D);
    u16* h1     = (u16*)alloc(sizeof(u16) * (size_t)NN * D);
    u16* h2     = (u16*)alloc(sizeof(u16) * (size_t)NN * D);
    u16* h3     = (u16*)alloc(sizeof(u16) * (size_t)NN * D);
    float* pooled = (float*)alloc(sizeof(float) * (size_t)NS * INR);
    float* wefft  = (float*)alloc(sizeof(float) * (size_t)INR * D);
    float* beff   = (float*)alloc(sizeof(float) * D);
    float* cw     = (float*)alloc(sizeof(float) * NL * TW * 16 * 48);
    float* cv     = (float*)alloc(sizeof(float) * NL * TW * 16);
    u16* packB    = (u16*)alloc(sizeof(u16) * NL * 8 * 4 * 64 * 8);

    hipMemsetAsync(zero_start, 0, zero_span, stream);

    prep_kernel<<<2836, 256, 0, stream>>>(pre_w, pre_b, post_w, cw, cv,
                                          op_w, op_b, bn_g, bn_b, bn_m, bn_v,
                                          wefft, beff, lin_w, packB, x, xbf,
                                          ei, sub, deg, scnt);
    scan2_kernel<<<2, 1024, 0, stream>>>(deg, eoff, scnt, soff);
    fill_kernel<<<(NE + 255) / 256, 256, 0, stream>>>(ei, sub, eoff, ecur, csr,
                                                      soff, scur, snodes);

    const u16* hs[4] = { xbf, h1, h2, h3 };
    for (int l = 0; l < NL; ++l) {
        fgu_kernel<<<NN / 16, 512, 0, stream>>>(hs[l], eoff, csr, deg, cw, cv,
                                                post_b, packB, lin_b,
                                                (u16*)hs[l + 1], l);
    }

    pool_kernel<<<NS, 128, 0, stream>>>(xbf, h1, h2, h3, soff, snodes, pooled);
    out_kernel<<<NS / 16, 512, 0, stream>>>(pooled, wefft, beff, out);
}

// Round 12
// 259.975 us; speedup vs baseline: 1.3523x; 1.0528x over previous
//
#include <hip/hip_runtime.h>
#include <cstdint>
#include <cstddef>

#define NN 20000   // nodes
#define NE 320000  // edges
#define D  128     // embed dim
#define TW 8       // towers
#define FT 16      // per-tower features
#define NL 3       // layers
#define NS 4096    // subgraphs
#define INR 512    // (L+1)*D
#define NTILES 1250
#define FGU_GRID 417

typedef unsigned short u16;
typedef __attribute__((ext_vector_type(8))) short short8;
typedef __attribute__((ext_vector_type(4))) float f32x4;

__device__ __forceinline__ float b2f(short s) {
    return __uint_as_float(((unsigned)(u16)s) << 16);
}
__device__ __forceinline__ u16 f2b(float f) {
    unsigned u = __float_as_uint(f);
    return (u16)((u + 0x7FFF + ((u >> 16) & 1)) >> 16);   // RNE
}

// ---------------- scan (block 0: deg->eoff over NN, block 1: scnt->soff over NS) ----

__global__ void scan2_kernel(const int* __restrict__ cnt0, int* __restrict__ off0,
                             const int* __restrict__ cnt1, int* __restrict__ off1) {
    __shared__ int lds[1024];
    const int tid = threadIdx.x;
    const int* cnt = blockIdx.x ? cnt1 : cnt0;
    int*       off = blockIdx.x ? off1 : off0;
    const int n   = blockIdx.x ? NS : NN;
    const int per = (n + 1023) >> 10;
    const int s = tid * per;
    const int e = min(s + per, n);
    int sum = 0;
    for (int i = s; i < e; ++i) sum += cnt[i];
    lds[tid] = sum;
    __syncthreads();
    for (int o = 1; o < 1024; o <<= 1) {
        int v = (tid >= o) ? lds[tid - o] : 0;
        __syncthreads();
        if (tid >= o) lds[tid] += v;
        __syncthreads();
    }
    int base = (tid == 0) ? 0 : lds[tid - 1];
    for (int i = s; i < e; ++i) { off[i] = base; base += cnt[i]; }
    if (tid == 1023) off[n] = lds[1023];
}

__global__ void fill_kernel(const int* __restrict__ ei, const int* __restrict__ sub,
                            const int* __restrict__ eoff, int* __restrict__ ecur,
                            int* __restrict__ csr,
                            const int* __restrict__ soff, int* __restrict__ scur,
                            int* __restrict__ snodes) {
    int i = blockIdx.x * blockDim.x + threadIdx.x;
    if (i < NE) {
        int dd = ei[NE + i];
        int p = atomicAdd(&ecur[dd], 1);
        csr[eoff[dd] + p] = ei[i];          // src
    }
    if (i < NN) {
        int g = sub[i];
        int p = atomicAdd(&scur[g], 1);
        snodes[soff[g] + p] = i;
    }
}

// ---------------- merged prep ----------------
// blocks: 0..23 cv-fold | 24..279 weff | 280..311 beff | 312..335 lin packB
//   | 336..1585 x->bf16 | 1586..2835 count | 2836..2859 tower packT (B13/B2 frags)
__global__ __launch_bounds__(256)
void prep_kernel(const float* __restrict__ pre_w, const float* __restrict__ pre_b,
                 const float* __restrict__ post_w,
                 float* __restrict__ cv,
                 const float* __restrict__ op_w, const float* __restrict__ op_b,
                 const float* __restrict__ gma, const float* __restrict__ bta,
                 const float* __restrict__ mean, const float* __restrict__ var,
                 float* __restrict__ wefft, float* __restrict__ beff,
                 const float* __restrict__ lin_w, u16* __restrict__ packB,
                 u16* __restrict__ packT,
                 const float* __restrict__ x, u16* __restrict__ xbf,
                 const int* __restrict__ ei, const int* __restrict__ sub,
                 int* __restrict__ deg, int* __restrict__ scnt) {
    const int b = blockIdx.x;
    const int tid = threadIdx.x;
    if (b < 24) {                          // ---- cv = postB . pre_b fold
        if (tid < 16) {
            const int lt = b;
            const float* QW = post_w + (size_t)lt * (FT * 2 * FT);
            const float* PB = pre_b  + (size_t)lt * FT;
            float v = 0.f;
            for (int k = 0; k < FT; ++k) v = fmaf(QW[tid * 32 + 16 + k], PB[k], v);
            cv[lt * 16 + tid] = v;
        }
    } else if (b < 280) {                  // ---- wefft[j][d] = op_w[d][j]*scale[j]
        int i = (b - 24) * 256 + tid;
        int j = i >> 7, d = i & (D - 1);
        float sc = gma[j] * rsqrtf(var[j] + 1e-5f);
        wefft[(size_t)j * D + d] = op_w[(size_t)d * INR + j] * sc;
    } else if (b < 312) {                  // ---- beff rows (4/block)
        const int d = (b - 280) * 4 + (tid >> 6);
        const int lane = tid & 63;
        float acc = 0.f;
        for (int j = lane; j < INR; j += 64) {
            float sc = gma[j] * rsqrtf(var[j] + 1e-5f);
            float sh = bta[j] - mean[j] * sc;
            acc = fmaf(op_w[(size_t)d * INR + j], sh, acc);
        }
#pragma unroll
        for (int o = 32; o; o >>= 1) acc += __shfl_down(acc, o);
        if (lane == 0) beff[d] = acc + op_b[d];
    } else if (b < 336) {                  // ---- pack lin_w into per-lane MFMA B-frags
        const int lt = b - 312;            // l*8 + ct
        const int l  = lt >> 3, ct = lt & 7;
        const int ks = tid >> 6;           // 0..3
        const int lane = tid & 63;
        const int col = ct * 16 + (lane & 15);
        const int k0  = ks * 32 + ((lane >> 4) & 3) * 8;
        const float* lw = lin_w + (size_t)l * D * D + (size_t)col * D + k0;
        u16* o = packB + ((size_t)(lt * 4 + ks) * 64 + lane) * 8;
#pragma unroll
        for (int j = 0; j < 8; ++j) o[j] = f2b(lw[j]);
    } else if (b < 1586) {                 // ---- x -> bf16 copy (2048 elems/block)
        const size_t base = (size_t)(b - 336) * 2048 + (size_t)tid * 8;
        float4 a = *(const float4*)(x + base);
        float4 c = *(const float4*)(x + base + 4);
        u16 o[8] = { f2b(a.x), f2b(a.y), f2b(a.z), f2b(a.w),
                     f2b(c.x), f2b(c.y), f2b(c.z), f2b(c.w) };
        uint4 u;
        u.x = (unsigned)o[0] | ((unsigned)o[1] << 16);
        u.y = (unsigned)o[2] | ((unsigned)o[3] << 16);
        u.z = (unsigned)o[4] | ((unsigned)o[5] << 16);
        u.w = (unsigned)o[6] | ((unsigned)o[7] << 16);
        *(uint4*)(xbf + base) = u;
    } else if (b < 2836) {                 // ---- count (deg / scnt atomics)
        int i = (b - 1586) * 256 + tid;
        if (i < NE) atomicAdd(&deg[ei[NE + i]], 1);
        if (i < NN) atomicAdd(&scnt[sub[i]], 1);
    } else {                               // ---- tower B-frags: B13=[M1;M3], B2=[M2;0]
        const int lt = b - 2836;           // l*8 + t
        if (tid < 128) {
            const int half = tid >> 6;     // 0: B13, 1: B2
            const int lane = tid & 63;
            const int cc = lane & 15;      // output col within tower
            const int j0 = (lane >> 4) * 8;
            const float* PW = pre_w  + (size_t)lt * (FT * 2 * FT);
            const float* QW = post_w + (size_t)lt * (FT * 2 * FT);
            u16 vals[8];
#pragma unroll
            for (int j = 0; j < 8; ++j) {
                const int k = j0 + j;
                float v = 0.f;
                if (half == 0) {
                    if (k < 16) v = QW[cc * 32 + k];                      // M1 = postA
                    else {                                                // M3 = postB.B
#pragma unroll
                        for (int kk = 0; kk < 16; ++kk)
                            v = fmaf(QW[cc * 32 + 16 + kk], PW[kk * 32 + 16 + (k - 16)], v);
                    }
                } else {
                    if (k < 16) {                                         // M2 = postB.A
#pragma unroll
                        for (int kk = 0; kk < 16; ++kk)
                            v = fmaf(QW[cc * 32 + 16 + kk], PW[kk * 32 + k], v);
                    }
                }
                vals[j] = f2b(v);
            }
            u16* o = packT + ((size_t)(lt * 2 + half) * 64 + lane) * 8;
#pragma unroll
            for (int j = 0; j < 8; ++j) o[j] = vals[j];
        }
    }
}

// ---------------- fused gather + PNA update (MFMA tower + MFMA lin) ----------------
// grid-stride over 16-node tiles; 512 threads (8 waves), 2 barriers/tile.
__global__ __launch_bounds__(512, 4)
void fgu_kernel(const u16* __restrict__ hin, const int* __restrict__ eoff,
                const int* __restrict__ csr, const int* __restrict__ deg,
                const float* __restrict__ cv, const float* __restrict__ post_b,
                const u16* __restrict__ packB, const u16* __restrict__ packT,
                const float* __restrict__ lin_b, u16* __restrict__ hout, int l) {
    __shared__ u16 XL [16 * 136];      // x rows, padded stride 136 (272 B)
    __shared__ u16 SGH[16 * 136];      // gathered sum hi bf16
    __shared__ u16 SGL[16 * 136];      // gathered sum lo bf16
    __shared__ u16 OBS[16 * 136];      // tower output bf16
    __shared__ float DG[16];

    const int tid  = threadIdx.x;
    const int lane = tid & 63;
    const int wv   = tid >> 6;         // 0..7 = column tile

    // lin B-frags (4 K-steps) + tower B-frags (1 K-step each)
    short8 BF[4];
    {
        const short8* pB = (const short8*)packB + (size_t)((l * 8 + wv) * 4) * 64 + lane;
#pragma unroll
        for (int ks = 0; ks < 4; ++ks) BF[ks] = pB[ks * 64];
    }
    const short8 BT13 = ((const short8*)packT)[(size_t)((l * 8 + wv) * 2 + 0) * 64 + lane];
    const short8 BT2  = ((const short8*)packT)[(size_t)((l * 8 + wv) * 2 + 1) * 64 + lane];
    const int cc   = lane & 15;
    const float bl   = lin_b [l * D + wv * 16 + cc];
    const float vq_s = cv    [(l * 8 + wv) * 16 + cc];
    const float cb_s = post_b[l * D + wv * 16 + cc];

    for (int tile = blockIdx.x; tile < NTILES; tile += FGU_GRID) {
        const int n0 = tile << 4;

        // ---- stage + gather: wave wv handles nodes 2wv, 2wv+1
        {
            const int half = lane >> 5;
            const int q    = lane & 31;
            const uint2* h2 = (const uint2*)hin;
#pragma unroll
            for (int u = 0; u < 2; ++u) {
                const int ln = wv * 2 + u;
                const int node = n0 + ln;
                ((unsigned*)XL)[ln * 68 + lane] =
                    ((const unsigned*)(hin + (size_t)node * D))[lane];
                if (lane == 0) DG[ln] = (float)deg[node];
                const int e0 = eoff[node], e1 = eoff[node + 1];
                float ax = 0.f, ay = 0.f, az = 0.f, aw = 0.f;
                int e = e0;
                for (; e + 16 <= e1; e += 16) {
                    int s0 = csr[e +  0 + half], s1 = csr[e +  2 + half];
                    int s2 = csr[e +  4 + half], s3 = csr[e +  6 + half];
                    int s4 = csr[e +  8 + half], s5 = csr[e + 10 + half];
                    int s6 = csr[e + 12 + half], s7 = csr[e + 14 + half];
                    uint2 v0 = h2[(size_t)s0 * 32 + q];
                    uint2 v1 = h2[(size_t)s1 * 32 + q];
                    uint2 v2 = h2[(size_t)s2 * 32 + q];
                    uint2 v3 = h2[(size_t)s3 * 32 + q];
                    uint2 v4 = h2[(size_t)s4 * 32 + q];
                    uint2 v5 = h2[(size_t)s5 * 32 + q];
                    uint2 v6 = h2[(size_t)s6 * 32 + q];
                    uint2 v7 = h2[(size_t)s7 * 32 + q];
                    ax += __uint_as_float(v0.x << 16) + __uint_as_float(v1.x << 16)
                        + __uint_as_float(v2.x << 16) + __uint_as_float(v3.x << 16)
                        + __uint_as_float(v4.x << 16) + __uint_as_float(v5.x << 16)
                        + __uint_as_float(v6.x << 16) + __uint_as_float(v7.x << 16);
                    ay += __uint_as_float(v0.x & 0xFFFF0000u) + __uint_as_float(v1.x & 0xFFFF0000u)
                        + __uint_as_float(v2.x & 0xFFFF0000u) + __uint_as_float(v3.x & 0xFFFF0000u)
                        + __uint_as_float(v4.x & 0xFFFF0000u) + __uint_as_float(v5.x & 0xFFFF0000u)
                        + __uint_as_float(v6.x & 0xFFFF0000u) + __uint_as_float(v7.x & 0xFFFF0000u);
                    az += __uint_as_float(v0.y << 16) + __uint_as_float(v1.y << 16)
                        + __uint_as_float(v2.y << 16) + __uint_as_float(v3.y << 16)
                        + __uint_as_float(v4.y << 16) + __uint_as_float(v5.y << 16)
                        + __uint_as_float(v6.y << 16) + __uint_as_float(v7.y << 16);
                    aw += __uint_as_float(v0.y & 0xFFFF0000u) + __uint_as_float(v1.y & 0xFFFF0000u)
                        + __uint_as_float(v2.y & 0xFFFF0000u) + __uint_as_float(v3.y & 0xFFFF0000u)
                        + __uint_as_float(v4.y & 0xFFFF0000u) + __uint_as_float(v5.y & 0xFFFF0000u)
                        + __uint_as_float(v6.y & 0xFFFF0000u) + __uint_as_float(v7.y & 0xFFFF0000u);
                }
                if (e + 8 <= e1) {
                    int s0 = csr[e + 0 + half], s1 = csr[e + 2 + half];
                    int s2 = csr[e + 4 + half], s3 = csr[e + 6 + half];
                    uint2 v0 = h2[(size_t)s0 * 32 + q];
                    uint2 v1 = h2[(size_t)s1 * 32 + q];
                    uint2 v2 = h2[(size_t)s2 * 32 + q];
                    uint2 v3 = h2[(size_t)s3 * 32 + q];
                    ax += __uint_as_float(v0.x << 16) + __uint_as_float(v1.x << 16)
                        + __uint_as_float(v2.x << 16) + __uint_as_float(v3.x << 16);
                    ay += __uint_as_float(v0.x & 0xFFFF0000u) + __uint_as_float(v1.x & 0xFFFF0000u)
                        + __uint_as_float(v2.x & 0xFFFF0000u) + __uint_as_float(v3.x & 0xFFFF0000u);
                    az += __uint_as_float(v0.y << 16) + __uint_as_float(v1.y << 16)
                        + __uint_as_float(v2.y << 16) + __uint_as_float(v3.y << 16);
                    aw += __uint_as_float(v0.y & 0xFFFF0000u) + __uint_as_float(v1.y & 0xFFFF0000u)
                        + __uint_as_float(v2.y & 0xFFFF0000u) + __uint_as_float(v3.y & 0xFFFF0000u);
                    e += 8;
                }
                for (; e < e1; e += 2) {
                    int idx = e + half;
                    bool valid = idx < e1;
                    int s = valid ? csr[idx] : 0;
                    uint2 v = h2[(size_t)s * 32 + q];
                    if (valid) {
                        ax += __uint_as_float(v.x << 16);
                        ay += __uint_as_float(v.x & 0xFFFF0000u);
                        az += __uint_as_float(v.y << 16);
                        aw += __uint_as_float(v.y & 0xFFFF0000u);
                    }
                }
                ax += __shfl_xor(ax, 32);
                ay += __shfl_xor(ay, 32);
                az += __shfl_xor(az, 32);
                aw += __shfl_xor(aw, 32);
                if (half == 0) {
                    u16 h0 = f2b(ax), h1 = f2b(ay), h2b = f2b(az), h3 = f2b(aw);
                    float r0 = ax - b2f(h0), r1 = ay - b2f(h1);
                    float r2 = az - b2f(h2b), r3 = aw - b2f(h3);
                    uint2 hv, lv;
                    hv.x = (unsigned)h0 | ((unsigned)h1 << 16);
                    hv.y = (unsigned)h2b | ((unsigned)h3 << 16);
                    lv.x = (unsigned)f2b(r0) | ((unsigned)f2b(r1) << 16);
                    lv.y = (unsigned)f2b(r2) | ((unsigned)f2b(r3) << 16);
                    *(uint2*)&SGH[ln * 136 + q * 4] = hv;
                    *(uint2*)&SGL[ln * 136 + q * 4] = lv;
                }
            }
        }
        __syncthreads();

        // ---- tower via MFMA: OB_tile = cb + M1x + M3s + deg*(M2x + vq)
        {
            const int arow   = lane & 15;      // node row of A
            const int achunk = lane >> 4;      // k-chunk 0..3
            const int coloff = wv * 16;
            const u16* ap = (achunk < 2)
                ? &XL [arow * 136 + coloff + achunk * 8]
                : &SGH[arow * 136 + coloff + (achunk - 2) * 8];
            short8 a1 = *(const short8*)ap;
            short8 sl = *(const short8*)&SGL[arow * 136 + coloff + (achunk & 1) * 8];
            short8 a2 = {0, 0, 0, 0, 0, 0, 0, 0};
            if (achunk >= 2) a2 = sl;
            f32x4 c1 = {0.f, 0.f, 0.f, 0.f};
            f32x4 c2 = {0.f, 0.f, 0.f, 0.f};
            c1 = __builtin_amdgcn_mfma_f32_16x16x32_bf16(a2, BT13, c1, 0, 0, 0);
            c1 = __builtin_amdgcn_mfma_f32_16x16x32_bf16(a1, BT13, c1, 0, 0, 0);
            c2 = __builtin_amdgcn_mfma_f32_16x16x32_bf16(a1, BT2,  c2, 0, 0, 0);
            const int rbase = (lane >> 4) * 4;
#pragma unroll
            for (int r = 0; r < 4; ++r) {
                float ob = cb_s + c1[r] + DG[rbase + r] * (c2[r] + vq_s);
                OBS[(rbase + r) * 136 + coloff + cc] = f2b(ob);
            }
        }
        __syncthreads();

        // ---- lin matvec: wave wv computes OUT[0:16][wv*16 : +16]
        {
            f32x4 c = {0.f, 0.f, 0.f, 0.f};
#pragma unroll
            for (int ks = 0; ks < 4; ++ks) {
                const short8 a = *(const short8*)((const char*)OBS +
                                    (lane & 15) * 272 + (ks * 4 + (lane >> 4)) * 16);
                c = __builtin_amdgcn_mfma_f32_16x16x32_bf16(a, BF[ks], c, 0, 0, 0);
            }
            const int d_epi = wv * 16 + cc;
#pragma unroll
            for (int r = 0; r < 4; ++r) {
                const int node = n0 + (lane >> 4) * 4 + r;
                float v = fmaxf(c[r] + bl, 0.f);
                hout[(size_t)node * D + d_epi] = f2b(v);
            }
        }
    }
}

// ---------------- pooling (bf16 in, fp32 out), 2-node unroll ----------------

__global__ __launch_bounds__(128)
void pool_kernel(const u16* __restrict__ h0, const u16* __restrict__ h1,
                 const u16* __restrict__ h2, const u16* __restrict__ h3,
                 const int* __restrict__ soff, const int* __restrict__ snodes,
                 float* __restrict__ pooled) {
    const int s = blockIdx.x;
    const int t = threadIdx.x;
    const int seg = t >> 5, q = t & 31;
    const u16* hs = (seg == 0) ? h0 : (seg == 1) ? h1 : (seg == 2) ? h2 : h3;
    const uint2* hv = (const uint2*)hs;
    const int a0 = soff[s], a1 = soff[s + 1];
    float ax = 0.f, ay = 0.f, az = 0.f, aw = 0.f;
    int a = a0;
    for (; a + 2 <= a1; a += 2) {
        int na = snodes[a], nb = snodes[a + 1];
        uint2 va = hv[(size_t)na * 32 + q];
        uint2 vb = hv[(size_t)nb * 32 + q];
        ax += __uint_as_float(va.x << 16) + __uint_as_float(vb.x << 16);
        ay += __uint_as_float(va.x & 0xFFFF0000u) + __uint_as_float(vb.x & 0xFFFF0000u);
        az += __uint_as_float(va.y << 16) + __uint_as_float(vb.y << 16);
        aw += __uint_as_float(va.y & 0xFFFF0000u) + __uint_as_float(vb.y & 0xFFFF0000u);
    }
    if (a < a1) {
        int n = snodes[a];
        uint2 v = hv[(size_t)n * 32 + q];
        ax += __uint_as_float(v.x << 16);
        ay += __uint_as_float(v.x & 0xFFFF0000u);
        az += __uint_as_float(v.y << 16);
        aw += __uint_as_float(v.y & 0xFFFF0000u);
    }
    float4 r; r.x = ax; r.y = ay; r.z = az; r.w = aw;
    ((float4*)pooled)[(size_t)s * 128 + seg * 32 + q] = r;
}

// ---------------- fused BN + out GEMM ----------------

__global__ __launch_bounds__(512)
void out_kernel(const float* __restrict__ pooled, const float* __restrict__ wefft,
                const float* __restrict__ beff, float* __restrict__ out) {
    __shared__ float sm[16 * INR];   // 32 KB; phase2 reuses as partial[4][16][128]
    const int tid = threadIdx.x;
    const int q = tid >> 7;
    const int d = tid & 127;
    const int s0 = blockIdx.x * 16;
    {
        const float4* src = (const float4*)(pooled + (size_t)s0 * INR);
        float4* dst = (float4*)sm;
        for (int i = tid; i < 16 * INR / 4; i += 512) dst[i] = src[i];
    }
    __syncthreads();
    float acc[16];
#pragma unroll
    for (int i = 0; i < 16; ++i) acc[i] = 0.f;
    for (int jj4 = 0; jj4 < 32; ++jj4) {
        const int j0 = q * 128 + jj4 * 4;
        float wv0 = wefft[(size_t)(j0 + 0) * D + d];
        float wv1 = wefft[(size_t)(j0 + 1) * D + d];
        float wv2 = wefft[(size_t)(j0 + 2) * D + d];
        float wv3 = wefft[(size_t)(j0 + 3) * D + d];
#pragma unroll
        for (int i = 0; i < 16; ++i) {
            float4 pv = *(const float4*)&sm[i * INR + j0];
            acc[i] = fmaf(pv.x, wv0, acc[i]);
            acc[i] = fmaf(pv.y, wv1, acc[i]);
            acc[i] = fmaf(pv.z, wv2, acc[i]);
            acc[i] = fmaf(pv.w, wv3, acc[i]);
        }
    }
    __syncthreads();
#pragma unroll
    for (int i = 0; i < 16; ++i) sm[(q * 16 + i) * 128 + d] = acc[i];
    __syncthreads();
    const float bb = beff[d];
#pragma unroll
    for (int ii = 0; ii < 4; ++ii) {
        int i = q * 4 + ii;
        float v = sm[i * 128 + d] + sm[(16 + i) * 128 + d]
                + sm[(32 + i) * 128 + d] + sm[(48 + i) * 128 + d];
        out[(size_t)(s0 + i) * D + d] = v + bb;
    }
}

// ---------------- launch ----------------

extern "C" void kernel_launch(void* const* d_in, const int* in_sizes, int n_in,
                              void* d_out, int out_size, void* d_ws, size_t ws_size,
                              hipStream_t stream) {
    const float* x      = (const float*)d_in[0];
    const int*   ei     = (const int*)d_in[1];
    const int*   sub    = (const int*)d_in[2];
    const float* pre_w  = (const float*)d_in[3];
    const float* pre_b  = (const float*)d_in[4];
    const float* post_w = (const float*)d_in[5];
    const float* post_b = (const float*)d_in[6];
    const float* lin_w  = (const float*)d_in[7];
    const float* lin_b  = (const float*)d_in[8];
    const float* bn_g   = (const float*)d_in[9];
    const float* bn_b   = (const float*)d_in[10];
    const float* bn_m   = (const float*)d_in[11];
    const float* bn_v   = (const float*)d_in[12];
    const float* op_w   = (const float*)d_in[13];
    const float* op_b   = (const float*)d_in[14];
    float* out = (float*)d_out;

    char* p = (char*)d_ws;
    auto alloc = [&](size_t bytes) -> char* {
        char* q = p;
        p += (bytes + 255) & ~(size_t)255;
        return q;
    };

    char* zero_start = p;
    int* deg  = (int*)alloc(sizeof(int) * NN);
    int* ecur = (int*)alloc(sizeof(int) * NN);
    int* scnt = (int*)alloc(sizeof(int) * NS);
    int* scur = (int*)alloc(sizeof(int) * NS);
    size_t zero_span = (size_t)(p - zero_start);

    int* eoff   = (int*)alloc(sizeof(int) * (NN + 1));
    int* soff   = (int*)alloc(sizeof(int) * (NS + 1));
    int* csr    = (int*)alloc(sizeof(int) * NE);
    int* snodes = (int*)alloc(sizeof(int) * NN);
    u16* xbf    = (u16*)alloc(sizeof(u16) * (size_t)NN * D);
    u16* h1     = (u16*)alloc(sizeof(u16) * (size_t)NN * D);
    u16* h2     = (u16*)alloc(sizeof(u16) * (size_t)NN * D);
    u16* h3     = (u16*)alloc(sizeof(u16) * (size_t)NN * D);
    float* pooled = (float*)alloc(sizeof(float) * (size_t)NS * INR);
    float* wefft  = (float*)alloc(sizeof(float) * (size_t)INR * D);
    float* beff   = (float*)alloc(sizeof(float) * D);
    float* cv     = (float*)alloc(sizeof(float) * NL * TW * 16);
    u16* packB    = (u16*)alloc(sizeof(u16) * NL * 8 * 4 * 64 * 8);
    u16* packT    = (u16*)alloc(sizeof(u16) * NL * 8 * 2 * 64 * 8);

    hipMemsetAsync(zero_start, 0, zero_span, stream);

    prep_kernel<<<2860, 256, 0, stream>>>(pre_w, pre_b, post_w, cv,
                                          op_w, op_b, bn_g, bn_b, bn_m, bn_v,
                                          wefft, beff, lin_w, packB, packT,
                                          x, xbf, ei, sub, deg, scnt);
    scan2_kernel<<<2, 1024, 0, stream>>>(deg, eoff, scnt, soff);
    fill_kernel<<<(NE + 255) / 256, 256, 0, stream>>>(ei, sub, eoff, ecur, csr,
                                                      soff, scur, snodes);

    const u16* hs[4] = { xbf, h1, h2, h3 };
    for (int l = 0; l < NL; ++l) {
        fgu_kernel<<<FGU_GRID, 512, 0, stream>>>(hs[l], eoff, csr, deg, cv,
                                                 post_b, packB, packT, lin_b,
                                                 (u16*)hs[l + 1], l);
    }

    pool_kernel<<<NS, 128, 0, stream>>>(xbf, h1, h2, h3, soff, snodes, pooled);
    out_kernel<<<NS / 16, 512, 0, stream>>>(pooled, wefft, beff, out);
}

// Round 14
// 252.742 us; speedup vs baseline: 1.3910x; 1.0286x over previous
//
#include <hip/hip_runtime.h>
#include <cstdint>
#include <cstddef>

#define NN 20000   // nodes
#define NE 320000  // edges
#define D  128     // embed dim
#define TW 8       // towers
#define FT 16      // per-tower features
#define NL 3       // layers
#define NS 4096    // subgraphs
#define INR 512    // (L+1)*D
#define NTILES 1250
#define FGU_GRID 417

typedef unsigned short u16;
typedef __attribute__((ext_vector_type(8))) short short8;
typedef __attribute__((ext_vector_type(4))) float f32x4;

__device__ __forceinline__ float b2f(short s) {
    return __uint_as_float(((unsigned)(u16)s) << 16);
}
__device__ __forceinline__ u16 f2b(float f) {
    unsigned u = __float_as_uint(f);
    return (u16)((u + 0x7FFF + ((u >> 16) & 1)) >> 16);   // RNE
}

// ---------------- scan (block 0: deg->eoff over NN, block 1: scnt->soff over NS) ----

__global__ void scan2_kernel(const int* __restrict__ cnt0, int* __restrict__ off0,
                             const int* __restrict__ cnt1, int* __restrict__ off1) {
    __shared__ int lds[1024];
    const int tid = threadIdx.x;
    const int* cnt = blockIdx.x ? cnt1 : cnt0;
    int*       off = blockIdx.x ? off1 : off0;
    const int n   = blockIdx.x ? NS : NN;
    const int per = (n + 1023) >> 10;
    const int s = tid * per;
    const int e = min(s + per, n);
    int sum = 0;
    for (int i = s; i < e; ++i) sum += cnt[i];
    lds[tid] = sum;
    __syncthreads();
    for (int o = 1; o < 1024; o <<= 1) {
        int v = (tid >= o) ? lds[tid - o] : 0;
        __syncthreads();
        if (tid >= o) lds[tid] += v;
        __syncthreads();
    }
    int base = (tid == 0) ? 0 : lds[tid - 1];
    for (int i = s; i < e; ++i) { off[i] = base; base += cnt[i]; }
    if (tid == 1023) off[n] = lds[1023];
}

__global__ void fill_kernel(const int* __restrict__ ei, const int* __restrict__ sub,
                            const int* __restrict__ eoff, int* __restrict__ ecur,
                            int* __restrict__ csr,
                            const int* __restrict__ soff, int* __restrict__ scur,
                            int* __restrict__ snodes) {
    int i = blockIdx.x * blockDim.x + threadIdx.x;
    if (i < NE) {
        int dd = ei[NE + i];
        int p = atomicAdd(&ecur[dd], 1);
        csr[eoff[dd] + p] = ei[i];          // src
    }
    if (i < NN) {
        int g = sub[i];
        int p = atomicAdd(&scur[g], 1);
        snodes[soff[g] + p] = i;
    }
}

// ---------------- merged prep ----------------
// blocks: 0..23 cv-fold | 24..279 weff | 280..311 beff | 312..335 lin packB
//   | 336..1585 x->bf16 | 1586..2835 count | 2836..2859 tower packT (B13/B2 frags)
__global__ __launch_bounds__(256)
void prep_kernel(const float* __restrict__ pre_w, const float* __restrict__ pre_b,
                 const float* __restrict__ post_w,
                 float* __restrict__ cv,
                 const float* __restrict__ op_w, const float* __restrict__ op_b,
                 const float* __restrict__ gma, const float* __restrict__ bta,
                 const float* __restrict__ mean, const float* __restrict__ var,
                 float* __restrict__ wefft, float* __restrict__ beff,
                 const float* __restrict__ lin_w, u16* __restrict__ packB,
                 u16* __restrict__ packT,
                 const float* __restrict__ x, u16* __restrict__ xbf,
                 const int* __restrict__ ei, const int* __restrict__ sub,
                 int* __restrict__ deg, int* __restrict__ scnt) {
    const int b = blockIdx.x;
    const int tid = threadIdx.x;
    if (b < 24) {                          // ---- cv = postB . pre_b fold
        if (tid < 16) {
            const int lt = b;
            const float* QW = post_w + (size_t)lt * (FT * 2 * FT);
            const float* PB = pre_b  + (size_t)lt * FT;
            float v = 0.f;
            for (int k = 0; k < FT; ++k) v = fmaf(QW[tid * 32 + 16 + k], PB[k], v);
            cv[lt * 16 + tid] = v;
        }
    } else if (b < 280) {                  // ---- wefft[j][d] = op_w[d][j]*scale[j]
        int i = (b - 24) * 256 + tid;
        int j = i >> 7, d = i & (D - 1);
        float sc = gma[j] * rsqrtf(var[j] + 1e-5f);
        wefft[(size_t)j * D + d] = op_w[(size_t)d * INR + j] * sc;
    } else if (b < 312) {                  // ---- beff rows (4/block)
        const int d = (b - 280) * 4 + (tid >> 6);
        const int lane = tid & 63;
        float acc = 0.f;
        for (int j = lane; j < INR; j += 64) {
            float sc = gma[j] * rsqrtf(var[j] + 1e-5f);
            float sh = bta[j] - mean[j] * sc;
            acc = fmaf(op_w[(size_t)d * INR + j], sh, acc);
        }
#pragma unroll
        for (int o = 32; o; o >>= 1) acc += __shfl_down(acc, o);
        if (lane == 0) beff[d] = acc + op_b[d];
    } else if (b < 336) {                  // ---- pack lin_w into per-lane MFMA B-frags
        const int lt = b - 312;            // l*8 + ct
        const int l  = lt >> 3, ct = lt & 7;
        const int ks = tid >> 6;           // 0..3
        const int lane = tid & 63;
        const int col = ct * 16 + (lane & 15);
        const int k0  = ks * 32 + ((lane >> 4) & 3) * 8;
        const float* lw = lin_w + (size_t)l * D * D + (size_t)col * D + k0;
        u16* o = packB + ((size_t)(lt * 4 + ks) * 64 + lane) * 8;
#pragma unroll
        for (int j = 0; j < 8; ++j) o[j] = f2b(lw[j]);
    } else if (b < 1586) {                 // ---- x -> bf16 copy (2048 elems/block)
        const size_t base = (size_t)(b - 336) * 2048 + (size_t)tid * 8;
        float4 a = *(const float4*)(x + base);
        float4 c = *(const float4*)(x + base + 4);
        u16 o[8] = { f2b(a.x), f2b(a.y), f2b(a.z), f2b(a.w),
                     f2b(c.x), f2b(c.y), f2b(c.z), f2b(c.w) };
        uint4 u;
        u.x = (unsigned)o[0] | ((unsigned)o[1] << 16);
        u.y = (unsigned)o[2] | ((unsigned)o[3] << 16);
        u.z = (unsigned)o[4] | ((unsigned)o[5] << 16);
        u.w = (unsigned)o[6] | ((unsigned)o[7] << 16);
        *(uint4*)(xbf + base) = u;
    } else if (b < 2836) {                 // ---- count (deg / scnt atomics)
        int i = (b - 1586) * 256 + tid;
        if (i < NE) atomicAdd(&deg[ei[NE + i]], 1);
        if (i < NN) atomicAdd(&scnt[sub[i]], 1);
    } else {                               // ---- tower B-frags: B13=[M1;M3], B2=[M2;0]
        const int lt = b - 2836;           // l*8 + t
        if (tid < 128) {
            const int half = tid >> 6;     // 0: B13, 1: B2
            const int lane = tid & 63;
            const int cc = lane & 15;      // output col within tower
            const int j0 = (lane >> 4) * 8;
            const float* PW = pre_w  + (size_t)lt * (FT * 2 * FT);
            const float* QW = post_w + (size_t)lt * (FT * 2 * FT);
            u16 vals[8];
#pragma unroll
            for (int j = 0; j < 8; ++j) {
                const int k = j0 + j;
                float v = 0.f;
                if (half == 0) {
                    if (k < 16) v = QW[cc * 32 + k];                      // M1 = postA
                    else {                                                // M3 = postB.B
#pragma unroll
                        for (int kk = 0; kk < 16; ++kk)
                            v = fmaf(QW[cc * 32 + 16 + kk], PW[kk * 32 + 16 + (k - 16)], v);
                    }
                } else {
                    if (k < 16) {                                         // M2 = postB.A
#pragma unroll
                        for (int kk = 0; kk < 16; ++kk)
                            v = fmaf(QW[cc * 32 + 16 + kk], PW[kk * 32 + k], v);
                    }
                }
                vals[j] = f2b(v);
            }
            u16* o = packT + ((size_t)(lt * 2 + half) * 64 + lane) * 8;
#pragma unroll
            for (int j = 0; j < 8; ++j) o[j] = vals[j];
        }
    }
}

// ---------------- fused gather + PNA update (MFMA tower + MFMA lin) ----------------
// grid-stride over 16-node tiles; 512 threads (8 waves), 2 barriers/tile.
// Phase G: half-wave per node (32 lanes x 8B = one row); both nodes of a wave
// progress in the same instruction stream -> 2x loads in flight, no shfl combine.
__global__ __launch_bounds__(512, 4)
void fgu_kernel(const u16* __restrict__ hin, const int* __restrict__ eoff,
                const int* __restrict__ csr, const int* __restrict__ deg,
                const float* __restrict__ cv, const float* __restrict__ post_b,
                const u16* __restrict__ packB, const u16* __restrict__ packT,
                const float* __restrict__ lin_b, u16* __restrict__ hout, int l) {
    __shared__ u16 XL [16 * 136];      // x rows, padded stride 136 (272 B)
    __shared__ u16 SGH[16 * 136];      // gathered sum hi bf16
    __shared__ u16 SGL[16 * 136];      // gathered sum lo bf16
    __shared__ u16 OBS[16 * 136];      // tower output bf16
    __shared__ float DG[16];

    const int tid  = threadIdx.x;
    const int lane = tid & 63;
    const int wv   = tid >> 6;         // 0..7 = column tile

    // lin B-frags (4 K-steps) + tower B-frags (1 K-step each)
    short8 BF[4];
    {
        const short8* pB = (const short8*)packB + (size_t)((l * 8 + wv) * 4) * 64 + lane;
#pragma unroll
        for (int ks = 0; ks < 4; ++ks) BF[ks] = pB[ks * 64];
    }
    const short8 BT13 = ((const short8*)packT)[(size_t)((l * 8 + wv) * 2 + 0) * 64 + lane];
    const short8 BT2  = ((const short8*)packT)[(size_t)((l * 8 + wv) * 2 + 1) * 64 + lane];
    const int cc   = lane & 15;
    const float bl   = lin_b [l * D + wv * 16 + cc];
    const float vq_s = cv    [(l * 8 + wv) * 16 + cc];
    const float cb_s = post_b[l * D + wv * 16 + cc];

    for (int tile = blockIdx.x; tile < NTILES; tile += FGU_GRID) {
        const int n0 = tile << 4;

        // ---- stage + gather: half-wave h handles node 2wv+h
        {
            const int half = lane >> 5;
            const int q    = lane & 31;
            const int ln   = wv * 2 + half;
            const int node = n0 + ln;
            const uint2* h2 = (const uint2*)hin;
            // stage x row (64 unsigned): each half stages its own node in 2 steps
            const unsigned* xr = (const unsigned*)(hin + (size_t)node * D);
            ((unsigned*)XL)[ln * 68 + q]      = xr[q];
            ((unsigned*)XL)[ln * 68 + 32 + q] = xr[32 + q];
            if (q == 0) DG[ln] = (float)deg[node];
            const int e0 = eoff[node], e1 = eoff[node + 1];
            float ax = 0.f, ay = 0.f, az = 0.f, aw = 0.f;
            int e = e0;
            for (; e + 16 <= e1; e += 16) {
                int s0 = csr[e + 0],  s1 = csr[e + 1],  s2 = csr[e + 2],  s3 = csr[e + 3];
                int s4 = csr[e + 4],  s5 = csr[e + 5],  s6 = csr[e + 6],  s7 = csr[e + 7];
                int s8 = csr[e + 8],  s9 = csr[e + 9],  sa = csr[e + 10], sb = csr[e + 11];
                int sc = csr[e + 12], sd = csr[e + 13], se = csr[e + 14], sf = csr[e + 15];
                uint2 v0 = h2[(size_t)s0 * 32 + q], v1 = h2[(size_t)s1 * 32 + q];
                uint2 v2 = h2[(size_t)s2 * 32 + q], v3 = h2[(size_t)s3 * 32 + q];
                uint2 v4 = h2[(size_t)s4 * 32 + q], v5 = h2[(size_t)s5 * 32 + q];
                uint2 v6 = h2[(size_t)s6 * 32 + q], v7 = h2[(size_t)s7 * 32 + q];
                uint2 v8 = h2[(size_t)s8 * 32 + q], v9 = h2[(size_t)s9 * 32 + q];
                uint2 va = h2[(size_t)sa * 32 + q], vb = h2[(size_t)sb * 32 + q];
                uint2 vc = h2[(size_t)sc * 32 + q], vd = h2[(size_t)sd * 32 + q];
                uint2 ve = h2[(size_t)se * 32 + q], vf = h2[(size_t)sf * 32 + q];
                ax += __uint_as_float(v0.x << 16) + __uint_as_float(v1.x << 16)
                    + __uint_as_float(v2.x << 16) + __uint_as_float(v3.x << 16)
                    + __uint_as_float(v4.x << 16) + __uint_as_float(v5.x << 16)
                    + __uint_as_float(v6.x << 16) + __uint_as_float(v7.x << 16)
                    + __uint_as_float(v8.x << 16) + __uint_as_float(v9.x << 16)
                    + __uint_as_float(va.x << 16) + __uint_as_float(vb.x << 16)
                    + __uint_as_float(vc.x << 16) + __uint_as_float(vd.x << 16)
                    + __uint_as_float(ve.x << 16) + __uint_as_float(vf.x << 16);
                ay += __uint_as_float(v0.x & 0xFFFF0000u) + __uint_as_float(v1.x & 0xFFFF0000u)
                    + __uint_as_float(v2.x & 0xFFFF0000u) + __uint_as_float(v3.x & 0xFFFF0000u)
                    + __uint_as_float(v4.x & 0xFFFF0000u) + __uint_as_float(v5.x & 0xFFFF0000u)
                    + __uint_as_float(v6.x & 0xFFFF0000u) + __uint_as_float(v7.x & 0xFFFF0000u)
                    + __uint_as_float(v8.x & 0xFFFF0000u) + __uint_as_float(v9.x & 0xFFFF0000u)
                    + __uint_as_float(va.x & 0xFFFF0000u) + __uint_as_float(vb.x & 0xFFFF0000u)
                    + __uint_as_float(vc.x & 0xFFFF0000u) + __uint_as_float(vd.x & 0xFFFF0000u)
                    + __uint_as_float(ve.x & 0xFFFF0000u) + __uint_as_float(vf.x & 0xFFFF0000u);
                az += __uint_as_float(v0.y << 16) + __uint_as_float(v1.y << 16)
                    + __uint_as_float(v2.y << 16) + __uint_as_float(v3.y << 16)
                    + __uint_as_float(v4.y << 16) + __uint_as_float(v5.y << 16)
                    + __uint_as_float(v6.y << 16) + __uint_as_float(v7.y << 16)
                    + __uint_as_float(v8.y << 16) + __uint_as_float(v9.y << 16)
                    + __uint_as_float(va.y << 16) + __uint_as_float(vb.y << 16)
                    + __uint_as_float(vc.y << 16) + __uint_as_float(vd.y << 16)
                    + __uint_as_float(ve.y << 16) + __uint_as_float(vf.y << 16);
                aw += __uint_as_float(v0.y & 0xFFFF0000u) + __uint_as_float(v1.y & 0xFFFF0000u)
                    + __uint_as_float(v2.y & 0xFFFF0000u) + __uint_as_float(v3.y & 0xFFFF0000u)
                    + __uint_as_float(v4.y & 0xFFFF0000u) + __uint_as_float(v5.y & 0xFFFF0000u)
                    + __uint_as_float(v6.y & 0xFFFF0000u) + __uint_as_float(v7.y & 0xFFFF0000u)
                    + __uint_as_float(v8.y & 0xFFFF0000u) + __uint_as_float(v9.y & 0xFFFF0000u)
                    + __uint_as_float(va.y & 0xFFFF0000u) + __uint_as_float(vb.y & 0xFFFF0000u)
                    + __uint_as_float(vc.y & 0xFFFF0000u) + __uint_as_float(vd.y & 0xFFFF0000u)
                    + __uint_as_float(ve.y & 0xFFFF0000u) + __uint_as_float(vf.y & 0xFFFF0000u);
            }
            if (e + 8 <= e1) {
                int s0 = csr[e + 0], s1 = csr[e + 1], s2 = csr[e + 2], s3 = csr[e + 3];
                int s4 = csr[e + 4], s5 = csr[e + 5], s6 = csr[e + 6], s7 = csr[e + 7];
                uint2 v0 = h2[(size_t)s0 * 32 + q], v1 = h2[(size_t)s1 * 32 + q];
                uint2 v2 = h2[(size_t)s2 * 32 + q], v3 = h2[(size_t)s3 * 32 + q];
                uint2 v4 = h2[(size_t)s4 * 32 + q], v5 = h2[(size_t)s5 * 32 + q];
                uint2 v6 = h2[(size_t)s6 * 32 + q], v7 = h2[(size_t)s7 * 32 + q];
                ax += __uint_as_float(v0.x << 16) + __uint_as_float(v1.x << 16)
                    + __uint_as_float(v2.x << 16) + __uint_as_float(v3.x << 16)
                    + __uint_as_float(v4.x << 16) + __uint_as_float(v5.x << 16)
                    + __uint_as_float(v6.x << 16) + __uint_as_float(v7.x << 16);
                ay += __uint_as_float(v0.x & 0xFFFF0000u) + __uint_as_float(v1.x & 0xFFFF0000u)
                    + __uint_as_float(v2.x & 0xFFFF0000u) + __uint_as_float(v3.x & 0xFFFF0000u)
                    + __uint_as_float(v4.x & 0xFFFF0000u) + __uint_as_float(v5.x & 0xFFFF0000u)
                    + __uint_as_float(v6.x & 0xFFFF0000u) + __uint_as_float(v7.x & 0xFFFF0000u);
                az += __uint_as_float(v0.y << 16) + __uint_as_float(v1.y << 16)
                    + __uint_as_float(v2.y << 16) + __uint_as_float(v3.y << 16)
                    + __uint_as_float(v4.y << 16) + __uint_as_float(v5.y << 16)
                    + __uint_as_float(v6.y << 16) + __uint_as_float(v7.y << 16);
                aw += __uint_as_float(v0.y & 0xFFFF0000u) + __uint_as_float(v1.y & 0xFFFF0000u)
                    + __uint_as_float(v2.y & 0xFFFF0000u) + __uint_as_float(v3.y & 0xFFFF0000u)
                    + __uint_as_float(v4.y & 0xFFFF0000u) + __uint_as_float(v5.y & 0xFFFF0000u)
                    + __uint_as_float(v6.y & 0xFFFF0000u) + __uint_as_float(v7.y & 0xFFFF0000u);
                e += 8;
            }
            for (; e < e1; ++e) {
                int s = csr[e];
                uint2 v = h2[(size_t)s * 32 + q];
                ax += __uint_as_float(v.x << 16);
                ay += __uint_as_float(v.x & 0xFFFF0000u);
                az += __uint_as_float(v.y << 16);
                aw += __uint_as_float(v.y & 0xFFFF0000u);
            }
            // split into hi/lo bf16 and store (each half owns row ln)
            u16 h0 = f2b(ax), h1 = f2b(ay), h2b = f2b(az), h3 = f2b(aw);
            float r0 = ax - b2f(h0), r1 = ay - b2f(h1);
            float r2 = az - b2f(h2b), r3 = aw - b2f(h3);
            uint2 hv, lv;
            hv.x = (unsigned)h0 | ((unsigned)h1 << 16);
            hv.y = (unsigned)h2b | ((unsigned)h3 << 16);
            lv.x = (unsigned)f2b(r0) | ((unsigned)f2b(r1) << 16);
            lv.y = (unsigned)f2b(r2) | ((unsigned)f2b(r3) << 16);
            *(uint2*)&SGH[ln * 136 + q * 4] = hv;
            *(uint2*)&SGL[ln * 136 + q * 4] = lv;
        }
        __syncthreads();

        // ---- tower via MFMA: OB_tile = cb + M1x + M3s + deg*(M2x + vq)
        {
            const int arow   = lane & 15;      // node row of A
            const int achunk = lane >> 4;      // k-chunk 0..3
            const int coloff = wv * 16;
            const u16* ap = (achunk < 2)
                ? &XL [arow * 136 + coloff + achunk * 8]
                : &SGH[arow * 136 + coloff + (achunk - 2) * 8];
            short8 a1 = *(const short8*)ap;
            short8 sl = *(const short8*)&SGL[arow * 136 + coloff + (achunk & 1) * 8];
            short8 a2 = {0, 0, 0, 0, 0, 0, 0, 0};
            if (achunk >= 2) a2 = sl;
            f32x4 c1 = {0.f, 0.f, 0.f, 0.f};
            f32x4 c2 = {0.f, 0.f, 0.f, 0.f};
            c1 = __builtin_amdgcn_mfma_f32_16x16x32_bf16(a2, BT13, c1, 0, 0, 0);
            c1 = __builtin_amdgcn_mfma_f32_16x16x32_bf16(a1, BT13, c1, 0, 0, 0);
            c2 = __builtin_amdgcn_mfma_f32_16x16x32_bf16(a1, BT2,  c2, 0, 0, 0);
            const int rbase = (lane >> 4) * 4;
#pragma unroll
            for (int r = 0; r < 4; ++r) {
                float ob = cb_s + c1[r] + DG[rbase + r] * (c2[r] + vq_s);
                OBS[(rbase + r) * 136 + coloff + cc] = f2b(ob);
            }
        }
        __syncthreads();

        // ---- lin matvec: wave wv computes OUT[0:16][wv*16 : +16]
        {
            f32x4 c = {0.f, 0.f, 0.f, 0.f};
#pragma unroll
            for (int ks = 0; ks < 4; ++ks) {
                const short8 a = *(const short8*)((const char*)OBS +
                                    (lane & 15) * 272 + (ks * 4 + (lane >> 4)) * 16);
                c = __builtin_amdgcn_mfma_f32_16x16x32_bf16(a, BF[ks], c, 0, 0, 0);
            }
            const int d_epi = wv * 16 + cc;
#pragma unroll
            for (int r = 0; r < 4; ++r) {
                const int node = n0 + (lane >> 4) * 4 + r;
                float v = fmaxf(c[r] + bl, 0.f);
                hout[(size_t)node * D + d_epi] = f2b(v);
            }
        }
    }
}

// ---------------- pooling (bf16 in, fp32 out), 2-node unroll ----------------

__global__ __launch_bounds__(128)
void pool_kernel(const u16* __restrict__ h0, const u16* __restrict__ h1,
                 const u16* __restrict__ h2, const u16* __restrict__ h3,
                 const int* __restrict__ soff, const int* __restrict__ snodes,
                 float* __restrict__ pooled) {
    const int s = blockIdx.x;
    const int t = threadIdx.x;
    const int seg = t >> 5, q = t & 31;
    const u16* hs = (seg == 0) ? h0 : (seg == 1) ? h1 : (seg == 2) ? h2 : h3;
    const uint2* hv = (const uint2*)hs;
    const int a0 = soff[s], a1 = soff[s + 1];
    float ax = 0.f, ay = 0.f, az = 0.f, aw = 0.f;
    int a = a0;
    for (; a + 2 <= a1; a += 2) {
        int na = snodes[a], nb = snodes[a + 1];
        uint2 va = hv[(size_t)na * 32 + q];
        uint2 vb = hv[(size_t)nb * 32 + q];
        ax += __uint_as_float(va.x << 16) + __uint_as_float(vb.x << 16);
        ay += __uint_as_float(va.x & 0xFFFF0000u) + __uint_as_float(vb.x & 0xFFFF0000u);
        az += __uint_as_float(va.y << 16) + __uint_as_float(vb.y << 16);
        aw += __uint_as_float(va.y & 0xFFFF0000u) + __uint_as_float(vb.y & 0xFFFF0000u);
    }
    if (a < a1) {
        int n = snodes[a];
        uint2 v = hv[(size_t)n * 32 + q];
        ax += __uint_as_float(v.x << 16);
        ay += __uint_as_float(v.x & 0xFFFF0000u);
        az += __uint_as_float(v.y << 16);
        aw += __uint_as_float(v.y & 0xFFFF0000u);
    }
    float4 r; r.x = ax; r.y = ay; r.z = az; r.w = aw;
    ((float4*)pooled)[(size_t)s * 128 + seg * 32 + q] = r;
}

// ---------------- fused BN + out GEMM ----------------

__global__ __launch_bounds__(512)
void out_kernel(const float* __restrict__ pooled, const float* __restrict__ wefft,
                const float* __restrict__ beff, float* __restrict__ out) {
    __shared__ float sm[16 * INR];   // 32 KB; phase2 reuses as partial[4][16][128]
    const int tid = threadIdx.x;
    const int q = tid >> 7;
    const int d = tid & 127;
    const int s0 = blockIdx.x * 16;
    {
        const float4* src = (const float4*)(pooled + (size_t)s0 * INR);
        float4* dst = (float4*)sm;
        for (int i = tid; i < 16 * INR / 4; i += 512) dst[i] = src[i];
    }
    __syncthreads();
    float acc[16];
#pragma unroll
    for (int i = 0; i < 16; ++i) acc[i] = 0.f;
    for (int jj4 = 0; jj4 < 32; ++jj4) {
        const int j0 = q * 128 + jj4 * 4;
        float wv0 = wefft[(size_t)(j0 + 0) * D + d];
        float wv1 = wefft[(size_t)(j0 + 1) * D + d];
        float wv2 = wefft[(size_t)(j0 + 2) * D + d];
        float wv3 = wefft[(size_t)(j0 + 3) * D + d];
#pragma unroll
        for (int i = 0; i < 16; ++i) {
            float4 pv = *(const float4*)&sm[i * INR + j0];
            acc[i] = fmaf(pv.x, wv0, acc[i]);
            acc[i] = fmaf(pv.y, wv1, acc[i]);
            acc[i] = fmaf(pv.z, wv2, acc[i]);
            acc[i] = fmaf(pv.w, wv3, acc[i]);
        }
    }
    __syncthreads();
#pragma unroll
    for (int i = 0; i < 16; ++i) sm[(q * 16 + i) * 128 + d] = acc[i];
    __syncthreads();
    const float bb = beff[d];
#pragma unroll
    for (int ii = 0; ii < 4; ++ii) {
        int i = q * 4 + ii;
        float v = sm[i * 128 + d] + sm[(16 + i) * 128 + d]
                + sm[(32 + i) * 128 + d] + sm[(48 + i) * 128 + d];
        out[(size_t)(s0 + i) * D + d] = v + bb;
    }
}

// ---------------- launch ----------------

extern "C" void kernel_launch(void* const* d_in, const int* in_sizes, int n_in,
                              void* d_out, int out_size, void* d_ws, size_t ws_size,
                              hipStream_t stream) {
    const float* x      = (const float*)d_in[0];
    const int*   ei     = (const int*)d_in[1];
    const int*   sub    = (const int*)d_in[2];
    const float* pre_w  = (const float*)d_in[3];
    const float* pre_b  = (const float*)d_in[4];
    const float* post_w = (const float*)d_in[5];
    const float* post_b = (const float*)d_in[6];
    const float* lin_w  = (const float*)d_in[7];
    const float* lin_b  = (const float*)d_in[8];
    const float* bn_g   = (const float*)d_in[9];
    const float* bn_b   = (const float*)d_in[10];
    const float* bn_m   = (const float*)d_in[11];
    const float* bn_v   = (const float*)d_in[12];
    const float* op_w   = (const float*)d_in[13];
    const float* op_b   = (const float*)d_in[14];
    float* out = (float*)d_out;

    char* p = (char*)d_ws;
    auto alloc = [&](size_t bytes) -> char* {
        char* q = p;
        p += (bytes + 255) & ~(size_t)255;
        return q;
    };

    char* zero_start = p;
    int* deg  = (int*)alloc(sizeof(int) * NN);
    int* ecur = (int*)alloc(sizeof(int) * NN);
    int* scnt = (int*)alloc(sizeof(int) * NS);
    int* scur = (int*)alloc(sizeof(int) * NS);
    size_t zero_span = (size_t)(p - zero_start);

    int* eoff   = (int*)alloc(sizeof(int) * (NN + 1));
    int* soff   = (int*)alloc(sizeof(int) * (NS + 1));
    int* csr    = (int*)alloc(sizeof(int) * NE);
    int* snodes = (int*)alloc(sizeof(int) * NN);
    u16* xbf    = (u16*)alloc(sizeof(u16) * (size_t)NN * D);
    u16* h1     = (u16*)alloc(sizeof(u16) * (size_t)NN * D);
    u16* h2     = (u16*)alloc(sizeof(u16) * (size_t)NN * D);
    u16* h3     = (u16*)alloc(sizeof(u16) * (size_t)NN * D);
    float* pooled = (float*)alloc(sizeof(float) * (size_t)NS * INR);
    float* wefft  = (float*)alloc(sizeof(float) * (size_t)INR * D);
    float* beff   = (float*)alloc(sizeof(float) * D);
    float* cv     = (float*)alloc(sizeof(float) * NL * TW * 16);
    u16* packB    = (u16*)alloc(sizeof(u16) * NL * 8 * 4 * 64 * 8);
    u16* packT    = (u16*)alloc(sizeof(u16) * NL * 8 * 2 * 64 * 8);

    hipMemsetAsync(zero_start, 0, zero_span, stream);

    prep_kernel<<<2860, 256, 0, stream>>>(pre_w, pre_b, post_w, cv,
                                          op_w, op_b, bn_g, bn_b, bn_m, bn_v,
                                          wefft, beff, lin_w, packB, packT,
                                          x, xbf, ei, sub, deg, scnt);
    scan2_kernel<<<2, 1024, 0, stream>>>(deg, eoff, scnt, soff);
    fill_kernel<<<(NE + 255) / 256, 256, 0, stream>>>(ei, sub, eoff, ecur, csr,
                                                      soff, scur, snodes);

    const u16* hs[4] = { xbf, h1, h2, h3 };
    for (int l = 0; l < NL; ++l) {
        fgu_kernel<<<FGU_GRID, 512, 0, stream>>>(hs[l], eoff, csr, deg, cv,
                                                 post_b, packB, packT, lin_b,
                                                 (u16*)hs[l + 1], l);
    }

    pool_kernel<<<NS, 128, 0, stream>>>(xbf, h1, h2, h3, soff, snodes, pooled);
    out_kernel<<<NS / 16, 512, 0, stream>>>(pooled, wefft, beff, out);
}